// Round 4
// baseline (314.987 us; speedup 1.0000x reference)
//
#include <hip/hip_runtime.h>
#include <stdint.h>

// Problem constants (MultiHeadAttention: S=2048, B=2, D=1024, H=16, Hd=64)
#define S_LEN 2048
#define BATCH 2
#define DM    1024
#define NH    16
#define HD    64
#define MROWS 4096            // GEMM rows, r = s*2 + b

typedef float f32x4 __attribute__((ext_vector_type(4)));
typedef short bfrag __attribute__((ext_vector_type(8)));   // 8 bf16 bit patterns (4 VGPRs)
typedef unsigned short u16x4_t __attribute__((ext_vector_type(4)));
typedef unsigned short u16x8_t __attribute__((ext_vector_type(8)));
typedef int i32x4_t __attribute__((ext_vector_type(4)));

#define EXP2F(x) __builtin_amdgcn_exp2f(x)

__device__ inline f32x4 mfma16(bfrag a, bfrag b, f32x4 c) {
    return __builtin_amdgcn_mfma_f32_16x16x32_bf16(a, b, c, 0, 0, 0);
}

// round-to-nearest-even-ish f32 -> bf16 bits
__device__ inline unsigned short bf16_rn(float x) {
    unsigned u = __builtin_bit_cast(unsigned, x);
    return (unsigned short)((u + 0x7fffu + ((u >> 16) & 1u)) >> 16);
}

// truncating hi/lo split: x ~= hi + lo with ~17 mantissa bits captured
__device__ inline void split_bf16(float x, unsigned short &h, unsigned short &l) {
    unsigned u = __builtin_bit_cast(unsigned, x);
    h = (unsigned short)(u >> 16);
    float hf = __builtin_bit_cast(float, u & 0xffff0000u);
    float r = x - hf;
    l = (unsigned short)(__builtin_bit_cast(unsigned, r) >> 16);
}

// pack two fp32 into two ROUND-HALF-UP bf16 in one b32 (lo = a, hi = b).
// +0x8000 kills truncation's -0.5ulp systematic bias (R3's accuracy failure).
__device__ inline unsigned pack_rhu(float a, float b) {
    unsigned ua = __builtin_bit_cast(unsigned, a) + 0x8000u;
    unsigned ub = __builtin_bit_cast(unsigned, b) + 0x8000u;
    return (ua >> 16) | (ub & 0xffff0000u);
}

// async global->LDS, 16B per lane; lds must be wave-uniform base (lane*16 implicit)
typedef __attribute__((address_space(1))) const unsigned int as1_u32;
typedef __attribute__((address_space(3))) unsigned int as3_u32;
__device__ inline void async16(void* lds, const void* g) {
    __builtin_amdgcn_global_load_lds((as1_u32*)g, (as3_u32*)lds, 16, 0, 0);
}

// ---------------------------------------------------------------------------
// Weight conversion: Wq/Wk/Wv -> bf16 planes (RN); Wo -> hi/lo bf16 planes.
// ---------------------------------------------------------------------------
__global__ __launch_bounds__(256)
void cvt_kernel(const float* __restrict__ Wq, const float* __restrict__ Wk,
                const float* __restrict__ Wv, const float* __restrict__ Wo,
                unsigned short* __restrict__ Wqb, unsigned short* __restrict__ Wkb,
                unsigned short* __restrict__ Wvb,
                unsigned short* __restrict__ Woh, unsigned short* __restrict__ Wol)
{
    const int z = blockIdx.z;
    size_t idx = ((size_t)blockIdx.x * 256 + threadIdx.x) * 8;
    if (idx >= (size_t)DM * DM) return;
    const float* src = (z == 0) ? Wq : (z == 1) ? Wk : (z == 2) ? Wv : Wo;
    float4 f0 = *(const float4*)&src[idx];
    float4 f1 = *(const float4*)&src[idx + 4];
    if (z < 3) {
        unsigned short* dst = (z == 0) ? Wqb : (z == 1) ? Wkb : Wvb;
        u16x8_t v = { bf16_rn(f0.x), bf16_rn(f0.y), bf16_rn(f0.z), bf16_rn(f0.w),
                      bf16_rn(f1.x), bf16_rn(f1.y), bf16_rn(f1.z), bf16_rn(f1.w) };
        *(u16x8_t*)&dst[idx] = v;
    } else {
        unsigned short h0,h1,h2,h3,h4,h5,h6,h7, l0,l1,l2,l3,l4,l5,l6,l7;
        split_bf16(f0.x,h0,l0); split_bf16(f0.y,h1,l1);
        split_bf16(f0.z,h2,l2); split_bf16(f0.w,h3,l3);
        split_bf16(f1.x,h4,l4); split_bf16(f1.y,h5,l5);
        split_bf16(f1.z,h6,l6); split_bf16(f1.w,h7,l7);
        u16x8_t vh = {h0,h1,h2,h3,h4,h5,h6,h7};
        u16x8_t vl = {l0,l1,l2,l3,l4,l5,l6,l7};
        *(u16x8_t*)&Woh[idx] = vh;
        *(u16x8_t*)&Wol[idx] = vl;
    }
}

// ---------------------------------------------------------------------------
// Q/K/V projection, m97-style: A (fp32) and W (bf16) staged via
// global_load_lds (16B, XOR-swizzled slots); A rounded (half-up) to bf16 at
// fragment assembly. 128x128 tile, BK=32, 8 waves (2x4 -> 64x32 each).
// XCD remap: id%8 selects an M-strip of 4 row-blocks (A L2 locality).
// z=0: Q (scale log2e/8) -> [b][h][s][d]; z=1: K -> same; z=2: V -> [b][h][d][s]
// ---------------------------------------------------------------------------
__global__ __launch_bounds__(512)
void qkv_gemm(const float* __restrict__ Qin, const float* __restrict__ Kin,
              const float* __restrict__ Vin,
              const unsigned short* __restrict__ Wqb,
              const unsigned short* __restrict__ Wkb,
              const unsigned short* __restrict__ Wvb,
              const float* __restrict__ bq, const float* __restrict__ bk,
              const float* __restrict__ bv,
              unsigned short* __restrict__ Qb, unsigned short* __restrict__ Kb,
              unsigned short* __restrict__ Vt)
{
    __shared__ float          sAf[128*32];   // 16 KB fp32 A tile
    __shared__ unsigned short sB [128*32];   // 8 KB bf16 W tile

    const int tid = threadIdx.x, lane = tid & 63, w8 = tid >> 6;
    const int m16 = lane & 15, q4 = lane >> 4;
    const int wr = w8 >> 2, wc = w8 & 3;
    const int z = blockIdx.z;

    // XCD-aware remap (256 blocks per z): XCD = id%8 owns M-strip of 4 blocks
    int id = blockIdx.x + 8 * blockIdx.y;
    int j  = id >> 3;
    const int m0 = ((id & 7) * 4 + (j & 3)) * 128;
    const int n0 = (j >> 2) * 128;

    const float* A    = (z == 0) ? Qin : (z == 1) ? Kin : Vin;
    const unsigned short* W = (z == 0) ? Wqb : (z == 1) ? Wkb : Wvb;
    const float* bias = (z == 0) ? bq : (z == 1) ? bk : bv;
    unsigned short* outp = (z == 0) ? Qb : (z == 1) ? Kb : Vt;

    // A staging: 1024 granules (16B = 4 fp32), 2 per thread; slot = granule id,
    // source column-granule XOR-swizzled by row for conflict-free frag reads.
    const int ar0 = tid >> 3,          ac0 = (tid & 7) ^ (ar0 & 7);
    const int ar1 = (tid + 512) >> 3,  ac1 = ((tid + 512) & 7) ^ (ar1 & 7);
    const float* gA0 = A + (size_t)(m0 + ar0) * DM + ac0 * 4;
    const float* gA1 = A + (size_t)(m0 + ar1) * DM + ac1 * 4;
    // B staging: 512 granules (16B = 8 bf16), 1 per thread
    const int br = tid >> 2,  bc = (tid & 3) ^ ((br ^ (br >> 2)) & 3);
    const unsigned short* gB = W + (size_t)(n0 + br) * DM + bc * 8;

    float*          ldsA0 = &sAf[w8 * 256];
    float*          ldsA1 = &sAf[2048 + w8 * 256];
    unsigned short* ldsB  = &sB [w8 * 512];

    // fragment LDS offsets (loop-invariant)
    int offA[4][2], offB[2];
    #pragma unroll
    for (int rt = 0; rt < 4; rt++) {
        int r = wr * 64 + rt * 16 + m16, s = r & 7;
        offA[rt][0] = r * 32 + ((q4 * 2 + 0) ^ s) * 4;
        offA[rt][1] = r * 32 + ((q4 * 2 + 1) ^ s) * 4;
    }
    #pragma unroll
    for (int ct = 0; ct < 2; ct++) {
        int r = wc * 32 + ct * 16 + m16;
        offB[ct] = r * 32 + ((q4 ^ ((r ^ (r >> 2)) & 3)) << 3);
    }

    f32x4 acc[4][2];
    const f32x4 zero4 = {0.f, 0.f, 0.f, 0.f};
    #pragma unroll
    for (int i = 0; i < 4; i++)
        #pragma unroll
        for (int jj = 0; jj < 2; jj++) acc[i][jj] = zero4;

    for (int k0 = 0; k0 < DM; k0 += 32) {
        async16(ldsA0, gA0);
        async16(ldsA1, gA1);
        async16(ldsB,  gB);
        gA0 += 32; gA1 += 32; gB += 32;
        __syncthreads();

        bfrag a[4], bb[2];
        #pragma unroll
        for (int rt = 0; rt < 4; rt++) {
            f32x4 lo = *(const f32x4*)&sAf[offA[rt][0]];
            f32x4 hi = *(const f32x4*)&sAf[offA[rt][1]];
            i32x4_t pk = { (int)pack_rhu(lo.x, lo.y), (int)pack_rhu(lo.z, lo.w),
                           (int)pack_rhu(hi.x, hi.y), (int)pack_rhu(hi.z, hi.w) };
            a[rt] = __builtin_bit_cast(bfrag, pk);
        }
        #pragma unroll
        for (int ct = 0; ct < 2; ct++)
            bb[ct] = *(const bfrag*)&sB[offB[ct]];

        #pragma unroll
        for (int rt = 0; rt < 4; rt++)
            #pragma unroll
            for (int ct = 0; ct < 2; ct++)
                acc[rt][ct] = mfma16(a[rt], bb[ct], acc[rt][ct]);
        __syncthreads();
    }

    const float SCALE = (z == 0) ? 0.18033688011112042f : 1.0f; // log2(e)/8
    #pragma unroll
    for (int rt = 0; rt < 4; rt++)
        #pragma unroll
        for (int ct = 0; ct < 2; ct++)
            #pragma unroll
            for (int reg = 0; reg < 4; reg++) {
                int r = m0 + wr * 64 + rt * 16 + q4 * 4 + reg;
                int c = n0 + wc * 32 + ct * 16 + m16;
                float v = (acc[rt][ct][reg] + bias[c]) * SCALE;
                int s = r >> 1, b = r & 1, hh = c >> 6, d = c & 63;
                unsigned short bv16 = bf16_rn(v);
                if (z == 2)
                    outp[((size_t)(b * NH + hh) * HD + d) * S_LEN + s] = bv16;
                else
                    outp[((size_t)(b * NH + hh) * S_LEN + s) * HD + d] = bv16;
            }
}

// ---------------------------------------------------------------------------
// Attention, transposed orientation, barrier-free:
//   S^T = K . Q^T ; C-layout gives lane = q-col, regs = t-rows -> P^T re-enters
//   the PV MFMA as a B-operand via a tiny per-wave LDS hop.
//   O^T = V^T . P^T. Fixed-base exp2 (scores pre-scaled by log2e/8 in Q) ->
//   additive partials, single l-reduction at the end. No __syncthreads.
// Block = 4 waves x 32 q-rows = 128 q; grid 512 linear; XCD remap groups the
// 16 blocks of one (b,h) on one XCD for K/V L2 residency.
// ---------------------------------------------------------------------------
__global__ __launch_bounds__(256)
void attn_kernel(const unsigned short* __restrict__ Qb,
                 const unsigned short* __restrict__ Kb,
                 const unsigned short* __restrict__ Vt,
                 unsigned short* __restrict__ Ap)
{
    __shared__ unsigned int sPT[4 * 32 * 36];  // per-wave 32 q x 32 t (b32 pairs), pad 36

    const int tid = threadIdx.x, lane = tid & 63, w4 = tid >> 6;
    const int m16 = lane & 15, q4 = lane >> 4;

    int id = blockIdx.x;                 // 0..511
    int xcd = id & 7, jj = id >> 3;      // jj 0..63
    const int bh = xcd * 4 + (jj >> 4);  // 4 heads per XCD
    const int qc = jj & 15;
    const int b = bh >> 4, h = bh & 15;
    const int qw = qc * 128 + w4 * 32;

    const unsigned short* Qp = Qb + (size_t)bh * (S_LEN * HD);
    const unsigned short* Kp = Kb + (size_t)bh * (S_LEN * HD);
    const unsigned short* Vp = Vt + (size_t)bh * (S_LEN * HD);
    unsigned int* pw = &sPT[w4 * 32 * 36];

    // Q B-fragments (fixed for whole kernel): [n=q=lane&15][k=d]
    bfrag aq[2][2];
    #pragma unroll
    for (int nt = 0; nt < 2; nt++)
        #pragma unroll
        for (int kc = 0; kc < 2; kc++)
            aq[nt][kc] = *(const bfrag*)&Qp[(size_t)(qw + nt*16 + m16) * HD + kc*32 + q4*8];

    const f32x4 zero4 = {0.f, 0.f, 0.f, 0.f};
    f32x4 O[2][4];
    float lp[2] = {0.f, 0.f};
    #pragma unroll
    for (int nt = 0; nt < 2; nt++)
        #pragma unroll
        for (int dt = 0; dt < 4; dt++) O[nt][dt] = zero4;

    for (int t0 = 0; t0 < S_LEN; t0 += 64) {
        // K A-frags [m=t][k=d] and V^T A-frags [m=d][k=t], direct from global
        bfrag ak[4][2], av[4][2];
        #pragma unroll
        for (int mt = 0; mt < 4; mt++)
            #pragma unroll
            for (int kc = 0; kc < 2; kc++) {
                ak[mt][kc] = *(const bfrag*)&Kp[(size_t)(t0 + mt*16 + m16) * HD + kc*32 + q4*8];
                av[mt][kc] = *(const bfrag*)&Vp[(size_t)(mt*16 + m16) * S_LEN + t0 + kc*32 + q4*8];
            }

        // S^T = K.Q^T, then p = exp2(s), round-half-up to bf16, stash P^T rows;
        // l accumulates the SAME rounded values PV will consume.
        #pragma unroll
        for (int nt = 0; nt < 2; nt++) {
            f32x4 Sc[4];
            #pragma unroll
            for (int mt = 0; mt < 4; mt++) {
                Sc[mt] = mfma16(ak[mt][0], aq[nt][0], zero4);
                Sc[mt] = mfma16(ak[mt][1], aq[nt][1], Sc[mt]);
            }
            unsigned rowb = (unsigned)(nt*16 + m16) * 36;
            #pragma unroll
            for (int mt = 0; mt < 4; mt++) {
                float p0 = EXP2F(Sc[mt][0]), p1 = EXP2F(Sc[mt][1]);
                float p2 = EXP2F(Sc[mt][2]), p3 = EXP2F(Sc[mt][3]);
                unsigned c0 = pack_rhu(p0, p1);
                unsigned c1 = pack_rhu(p2, p3);
                float r0 = __builtin_bit_cast(float, c0 << 16);
                float r1 = __builtin_bit_cast(float, c0 & 0xffff0000u);
                float r2 = __builtin_bit_cast(float, c1 << 16);
                float r3 = __builtin_bit_cast(float, c1 & 0xffff0000u);
                lp[nt] += (r0 + r1) + (r2 + r3);
                uint2 c2 = { c0, c1 };
                *(uint2*)&pw[rowb + mt*8 + q4*2] = c2;
            }
        }

        // O^T += V^T . P^T  (P^T B-frags: [n=q=lane&15][k=t=quad*8+j])
        #pragma unroll
        for (int nt = 0; nt < 2; nt++) {
            bfrag bp[2];
            #pragma unroll
            for (int kc = 0; kc < 2; kc++)
                bp[kc] = __builtin_bit_cast(bfrag,
                    *(const i32x4_t*)&pw[(unsigned)(nt*16 + m16) * 36 + kc*16 + q4*4]);
            #pragma unroll
            for (int dt = 0; dt < 4; dt++) {
                O[nt][dt] = mfma16(av[dt][0], bp[0], O[nt][dt]);
                O[nt][dt] = mfma16(av[dt][1], bp[1], O[nt][dt]);
            }
        }
    }

    // epilogue: reduce l over the 4 quad-lanes holding the same q, normalize,
    // write RN bf16 attn plane [r = s*2+b][h*64+d]
    #pragma unroll
    for (int nt = 0; nt < 2; nt++) {
        float l = lp[nt];
        l += __shfl_xor(l, 16);
        l += __shfl_xor(l, 32);
        float inv = 1.0f / l;
        int q = qw + nt*16 + m16;
        size_t rb = ((size_t)q * BATCH + b) * DM + h * 64;
        #pragma unroll
        for (int dt = 0; dt < 4; dt++) {
            u16x4_t o = { bf16_rn(O[nt][dt][0] * inv), bf16_rn(O[nt][dt][1] * inv),
                          bf16_rn(O[nt][dt][2] * inv), bf16_rn(O[nt][dt][3] * inv) };
            *(u16x4_t*)&Ap[rb + dt*16 + q4*4] = o;
        }
    }
}

// ---------------------------------------------------------------------------
// Out projection: d_out = attn @ Wo^T + bo (fp32). 2-phase split on W:
// acc = A.Wh + A.Wl (A = RN-bf16 attn plane; dropped Al.Wh term is ~2.5e-4).
// All staging via global_load_lds. 128x128 tile, BK=32, 8 waves. XCD remap.
// ---------------------------------------------------------------------------
__global__ __launch_bounds__(512)
void out_gemm(const unsigned short* __restrict__ Ap,
              const unsigned short* __restrict__ Woh,
              const unsigned short* __restrict__ Wol,
              const float* __restrict__ bo, float* __restrict__ out)
{
    __shared__ unsigned short sA[128*32];
    __shared__ unsigned short sH[128*32];
    __shared__ unsigned short sL[128*32];

    const int tid = threadIdx.x, lane = tid & 63, w8 = tid >> 6;
    const int m16 = lane & 15, q4 = lane >> 4;
    const int wr = w8 >> 2, wc = w8 & 3;

    int id = blockIdx.x + 8 * blockIdx.y;
    int j  = id >> 3;
    const int m0 = ((id & 7) * 4 + (j & 3)) * 128;
    const int n0 = (j >> 2) * 128;

    const int br = tid >> 2,  bc = (tid & 3) ^ ((br ^ (br >> 2)) & 3);
    const unsigned short* gA = Ap  + (size_t)(m0 + br) * DM + bc * 8;
    const unsigned short* gH = Woh + (size_t)(n0 + br) * DM + bc * 8;
    const unsigned short* gL = Wol + (size_t)(n0 + br) * DM + bc * 8;
    unsigned short* ldsA = &sA[w8 * 512];
    unsigned short* ldsH = &sH[w8 * 512];
    unsigned short* ldsL = &sL[w8 * 512];

    int offA[4], offB[2];
    #pragma unroll
    for (int rt = 0; rt < 4; rt++) {
        int r = wr * 64 + rt * 16 + m16;
        offA[rt] = r * 32 + ((q4 ^ ((r ^ (r >> 2)) & 3)) << 3);
    }
    #pragma unroll
    for (int ct = 0; ct < 2; ct++) {
        int r = wc * 32 + ct * 16 + m16;
        offB[ct] = r * 32 + ((q4 ^ ((r ^ (r >> 2)) & 3)) << 3);
    }

    f32x4 acc[4][2];
    const f32x4 zero4 = {0.f, 0.f, 0.f, 0.f};
    #pragma unroll
    for (int i = 0; i < 4; i++)
        #pragma unroll
        for (int jj = 0; jj < 2; jj++) acc[i][jj] = zero4;

    for (int k0 = 0; k0 < DM; k0 += 32) {
        async16(ldsA, gA);
        async16(ldsH, gH);
        async16(ldsL, gL);
        gA += 32; gH += 32; gL += 32;
        __syncthreads();

        bfrag a[4], bh2[2], bl2[2];
        #pragma unroll
        for (int rt = 0; rt < 4; rt++) a[rt] = *(const bfrag*)&sA[offA[rt]];
        #pragma unroll
        for (int ct = 0; ct < 2; ct++) {
            bh2[ct] = *(const bfrag*)&sH[offB[ct]];
            bl2[ct] = *(const bfrag*)&sL[offB[ct]];
        }
        #pragma unroll
        for (int rt = 0; rt < 4; rt++)
            #pragma unroll
            for (int ct = 0; ct < 2; ct++) {
                acc[rt][ct] = mfma16(a[rt], bh2[ct], acc[rt][ct]);
                acc[rt][ct] = mfma16(a[rt], bl2[ct], acc[rt][ct]);
            }
        __syncthreads();
    }

    #pragma unroll
    for (int rt = 0; rt < 4; rt++)
        #pragma unroll
        for (int ct = 0; ct < 2; ct++)
            #pragma unroll
            for (int reg = 0; reg < 4; reg++) {
                int r = m0 + wr * 64 + rt * 16 + q4 * 4 + reg;
                int c = n0 + wc * 32 + ct * 16 + m16;
                out[(size_t)r * DM + c] = acc[rt][ct][reg] + bo[c];
            }
}

// ---------------------------------------------------------------------------
extern "C" void kernel_launch(void* const* d_in, const int* in_sizes, int n_in,
                              void* d_out, int out_size, void* d_ws, size_t ws_size,
                              hipStream_t stream)
{
    const float* query = (const float*)d_in[0];
    const float* key   = (const float*)d_in[1];
    const float* value = (const float*)d_in[2];
    const float* Wq    = (const float*)d_in[3];
    const float* bq    = (const float*)d_in[4];
    const float* Wk    = (const float*)d_in[5];
    const float* bk    = (const float*)d_in[6];
    const float* Wv    = (const float*)d_in[7];
    const float* bv    = (const float*)d_in[8];
    const float* Wo    = (const float*)d_in[9];
    const float* bo    = (const float*)d_in[10];

    char* ws = (char*)d_ws;
    const size_t MB = 1u << 20;
    unsigned short* Qb  = (unsigned short*)(ws);            //  0..8 MB
    unsigned short* Kb  = (unsigned short*)(ws +  8*MB);    //  8..16
    unsigned short* Vt  = (unsigned short*)(ws + 16*MB);    // 16..24
    unsigned short* Woh = (unsigned short*)(ws + 24*MB);    // 24..26 (live till out_gemm)
    unsigned short* Wol = (unsigned short*)(ws + 26*MB);    // 26..28
    unsigned short* Wqb = (unsigned short*)(ws + 28*MB);    // 28..30 (dead after qkv)
    unsigned short* Wkb = (unsigned short*)(ws + 30*MB);    // 30..32
    unsigned short* Wvb = (unsigned short*)(ws + 32*MB);    // 32..34
    unsigned short* Ap  = (unsigned short*)(ws + 28*MB);    // 28..36, aliases Wqb/Wkb/Wvb
    // peak footprint: 36 MB (<= validated 40 MB)

    cvt_kernel<<<dim3(512, 1, 4), 256, 0, stream>>>(
        Wq, Wk, Wv, Wo, Wqb, Wkb, Wvb, Woh, Wol);
    qkv_gemm<<<dim3(8, 32, 3), 512, 0, stream>>>(
        query, key, value, Wqb, Wkb, Wvb, bq, bk, bv, Qb, Kb, Vt);
    attn_kernel<<<dim3(512), 256, 0, stream>>>(Qb, Kb, Vt, Ap);
    out_gemm<<<dim3(8, 32), 512, 0, stream>>>(Ap, Woh, Wol, bo, (float*)d_out);
}

// Round 6
// 256.277 us; speedup vs baseline: 1.2291x; 1.2291x over previous
//
#include <hip/hip_runtime.h>
#include <stdint.h>

// Problem constants (MultiHeadAttention: S=2048, B=2, D=1024, H=16, Hd=64)
#define S_LEN 2048
#define BATCH 2
#define DM    1024
#define NH    16
#define HD    64
#define MROWS 4096            // GEMM rows, r = s*2 + b

typedef float f32x4 __attribute__((ext_vector_type(4)));
typedef short bfrag __attribute__((ext_vector_type(8)));   // 8 bf16 bit patterns (4 VGPRs)
typedef unsigned short u16x4_t __attribute__((ext_vector_type(4)));
typedef unsigned short u16x8_t __attribute__((ext_vector_type(8)));
typedef int i32x4_t __attribute__((ext_vector_type(4)));

#define EXP2F(x) __builtin_amdgcn_exp2f(x)

__device__ inline f32x4 mfma16(bfrag a, bfrag b, f32x4 c) {
    return __builtin_amdgcn_mfma_f32_16x16x32_bf16(a, b, c, 0, 0, 0);
}

// round-to-nearest-even-ish f32 -> bf16 bits
__device__ inline unsigned short bf16_rn(float x) {
    unsigned u = __builtin_bit_cast(unsigned, x);
    return (unsigned short)((u + 0x7fffu + ((u >> 16) & 1u)) >> 16);
}

// truncating hi/lo split: x ~= hi + lo with ~17 mantissa bits captured
__device__ inline void split_bf16(float x, unsigned short &h, unsigned short &l) {
    unsigned u = __builtin_bit_cast(unsigned, x);
    h = (unsigned short)(u >> 16);
    float hf = __builtin_bit_cast(float, u & 0xffff0000u);
    float r = x - hf;
    l = (unsigned short)(__builtin_bit_cast(unsigned, r) >> 16);
}

// pack two fp32 into two ROUND-HALF-UP bf16 in one b32 (lo = a, hi = b).
// +0x8000 kills truncation's -0.5ulp systematic bias (R3's accuracy failure).
__device__ inline unsigned pack_rhu(float a, float b) {
    unsigned ua = __builtin_bit_cast(unsigned, a) + 0x8000u;
    unsigned ub = __builtin_bit_cast(unsigned, b) + 0x8000u;
    return (ua >> 16) | (ub & 0xffff0000u);
}

// async global->LDS, 16B per lane; lds must be wave-uniform base (lane*16 implicit)
typedef __attribute__((address_space(1))) const unsigned int as1_u32;
typedef __attribute__((address_space(3))) unsigned int as3_u32;
__device__ inline void async16(void* lds, const void* g) {
    __builtin_amdgcn_global_load_lds((as1_u32*)g, (as3_u32*)lds, 16, 0, 0);
}

// ---------------------------------------------------------------------------
// Weight conversion: Wq/Wk/Wv -> bf16 planes (RN); Wo -> hi/lo bf16 planes.
// ---------------------------------------------------------------------------
__global__ __launch_bounds__(256)
void cvt_kernel(const float* __restrict__ Wq, const float* __restrict__ Wk,
                const float* __restrict__ Wv, const float* __restrict__ Wo,
                unsigned short* __restrict__ Wqb, unsigned short* __restrict__ Wkb,
                unsigned short* __restrict__ Wvb,
                unsigned short* __restrict__ Woh, unsigned short* __restrict__ Wol)
{
    const int z = blockIdx.z;
    size_t idx = ((size_t)blockIdx.x * 256 + threadIdx.x) * 8;
    if (idx >= (size_t)DM * DM) return;
    const float* src = (z == 0) ? Wq : (z == 1) ? Wk : (z == 2) ? Wv : Wo;
    float4 f0 = *(const float4*)&src[idx];
    float4 f1 = *(const float4*)&src[idx + 4];
    if (z < 3) {
        unsigned short* dst = (z == 0) ? Wqb : (z == 1) ? Wkb : Wvb;
        u16x8_t v = { bf16_rn(f0.x), bf16_rn(f0.y), bf16_rn(f0.z), bf16_rn(f0.w),
                      bf16_rn(f1.x), bf16_rn(f1.y), bf16_rn(f1.z), bf16_rn(f1.w) };
        *(u16x8_t*)&dst[idx] = v;
    } else {
        unsigned short h0,h1,h2,h3,h4,h5,h6,h7, l0,l1,l2,l3,l4,l5,l6,l7;
        split_bf16(f0.x,h0,l0); split_bf16(f0.y,h1,l1);
        split_bf16(f0.z,h2,l2); split_bf16(f0.w,h3,l3);
        split_bf16(f1.x,h4,l4); split_bf16(f1.y,h5,l5);
        split_bf16(f1.z,h6,l6); split_bf16(f1.w,h7,l7);
        u16x8_t vh = {h0,h1,h2,h3,h4,h5,h6,h7};
        u16x8_t vl = {l0,l1,l2,l3,l4,l5,l6,l7};
        *(u16x8_t*)&Woh[idx] = vh;
        *(u16x8_t*)&Wol[idx] = vl;
    }
}

// ---------------------------------------------------------------------------
// Q/K/V projection, m97-style: A (fp32) and W (bf16) staged via
// global_load_lds (16B, XOR-swizzled slots); A rounded (half-up) to bf16 at
// fragment assembly. 128x128 tile, BK=32, 8 waves (2x4 -> 64x32 each).
// XCD remap: id%8 selects an M-strip of 4 row-blocks (A L2 locality).
// z=0: Q (scale log2e/8) -> [b][h][s][d]; z=1: K -> same; z=2: V -> [b][h][d][s]
// ---------------------------------------------------------------------------
__global__ __launch_bounds__(512)
void qkv_gemm(const float* __restrict__ Qin, const float* __restrict__ Kin,
              const float* __restrict__ Vin,
              const unsigned short* __restrict__ Wqb,
              const unsigned short* __restrict__ Wkb,
              const unsigned short* __restrict__ Wvb,
              const float* __restrict__ bq, const float* __restrict__ bk,
              const float* __restrict__ bv,
              unsigned short* __restrict__ Qb, unsigned short* __restrict__ Kb,
              unsigned short* __restrict__ Vt)
{
    __shared__ float          sAf[128*32];   // 16 KB fp32 A tile
    __shared__ unsigned short sB [128*32];   // 8 KB bf16 W tile

    const int tid = threadIdx.x, lane = tid & 63, w8 = tid >> 6;
    const int m16 = lane & 15, q4 = lane >> 4;
    const int wr = w8 >> 2, wc = w8 & 3;
    const int z = blockIdx.z;

    // XCD-aware remap (256 blocks per z): XCD = id%8 owns M-strip of 4 blocks
    int id = blockIdx.x + 8 * blockIdx.y;
    int j  = id >> 3;
    const int m0 = ((id & 7) * 4 + (j & 3)) * 128;
    const int n0 = (j >> 2) * 128;

    const float* A    = (z == 0) ? Qin : (z == 1) ? Kin : Vin;
    const unsigned short* W = (z == 0) ? Wqb : (z == 1) ? Wkb : Wvb;
    const float* bias = (z == 0) ? bq : (z == 1) ? bk : bv;
    unsigned short* outp = (z == 0) ? Qb : (z == 1) ? Kb : Vt;

    // A staging: 1024 granules (16B = 4 fp32), 2 per thread; slot = granule id,
    // source column-granule XOR-swizzled by row for conflict-free frag reads.
    const int ar0 = tid >> 3,          ac0 = (tid & 7) ^ (ar0 & 7);
    const int ar1 = (tid + 512) >> 3,  ac1 = ((tid + 512) & 7) ^ (ar1 & 7);
    const float* gA0 = A + (size_t)(m0 + ar0) * DM + ac0 * 4;
    const float* gA1 = A + (size_t)(m0 + ar1) * DM + ac1 * 4;
    // B staging: 512 granules (16B = 8 bf16), 1 per thread
    const int br = tid >> 2,  bc = (tid & 3) ^ ((br ^ (br >> 2)) & 3);
    const unsigned short* gB = W + (size_t)(n0 + br) * DM + bc * 8;

    float*          ldsA0 = &sAf[w8 * 256];
    float*          ldsA1 = &sAf[2048 + w8 * 256];
    unsigned short* ldsB  = &sB [w8 * 512];

    // fragment LDS offsets (loop-invariant)
    int offA[4][2], offB[2];
    #pragma unroll
    for (int rt = 0; rt < 4; rt++) {
        int r = wr * 64 + rt * 16 + m16, s = r & 7;
        offA[rt][0] = r * 32 + ((q4 * 2 + 0) ^ s) * 4;
        offA[rt][1] = r * 32 + ((q4 * 2 + 1) ^ s) * 4;
    }
    #pragma unroll
    for (int ct = 0; ct < 2; ct++) {
        int r = wc * 32 + ct * 16 + m16;
        offB[ct] = r * 32 + ((q4 ^ ((r ^ (r >> 2)) & 3)) << 3);
    }

    f32x4 acc[4][2];
    const f32x4 zero4 = {0.f, 0.f, 0.f, 0.f};
    #pragma unroll
    for (int i = 0; i < 4; i++)
        #pragma unroll
        for (int jj = 0; jj < 2; jj++) acc[i][jj] = zero4;

    for (int k0 = 0; k0 < DM; k0 += 32) {
        async16(ldsA0, gA0);
        async16(ldsA1, gA1);
        async16(ldsB,  gB);
        gA0 += 32; gA1 += 32; gB += 32;
        __syncthreads();

        bfrag a[4], bb[2];
        #pragma unroll
        for (int rt = 0; rt < 4; rt++) {
            f32x4 lo = *(const f32x4*)&sAf[offA[rt][0]];
            f32x4 hi = *(const f32x4*)&sAf[offA[rt][1]];
            i32x4_t pk = { (int)pack_rhu(lo.x, lo.y), (int)pack_rhu(lo.z, lo.w),
                           (int)pack_rhu(hi.x, hi.y), (int)pack_rhu(hi.z, hi.w) };
            a[rt] = __builtin_bit_cast(bfrag, pk);
        }
        #pragma unroll
        for (int ct = 0; ct < 2; ct++)
            bb[ct] = *(const bfrag*)&sB[offB[ct]];

        #pragma unroll
        for (int rt = 0; rt < 4; rt++)
            #pragma unroll
            for (int ct = 0; ct < 2; ct++)
                acc[rt][ct] = mfma16(a[rt], bb[ct], acc[rt][ct]);
        __syncthreads();
    }

    const float SCALE = (z == 0) ? 0.18033688011112042f : 1.0f; // log2(e)/8
    #pragma unroll
    for (int rt = 0; rt < 4; rt++)
        #pragma unroll
        for (int ct = 0; ct < 2; ct++)
            #pragma unroll
            for (int reg = 0; reg < 4; reg++) {
                int r = m0 + wr * 64 + rt * 16 + q4 * 4 + reg;
                int c = n0 + wc * 32 + ct * 16 + m16;
                float v = (acc[rt][ct][reg] + bias[c]) * SCALE;
                int s = r >> 1, b = r & 1, hh = c >> 6, d = c & 63;
                unsigned short bv16 = bf16_rn(v);
                if (z == 2)
                    outp[((size_t)(b * NH + hh) * HD + d) * S_LEN + s] = bv16;
                else
                    outp[((size_t)(b * NH + hh) * S_LEN + s) * HD + d] = bv16;
            }
}

// ---------------------------------------------------------------------------
// Attention, transposed orientation, LDS-staged + double-buffered K/V:
//   R4's per-wave global fragment reads made every wave re-read the whole
//   K/V tile at 64B/128B-line efficiency -> ~2.1 GB L2 traffic (L2-BW-bound,
//   126 us). Now the block stages K (8KB) and V^T (8KB) per t-tile into LDS
//   via global_load_lds (async, no VGPRs), double-buffered with the prefetch
//   issued right after the single per-iteration barrier.
//   S^T = K.Q^T ; C-layout gives lane = q-col, regs = t-rows -> P^T re-enters
//   the PV MFMA as a B-operand via a tiny per-wave LDS hop. O^T = V^T.P^T.
//   Fixed-base exp2 (Q pre-scaled by log2e/8) -> additive partials, one
//   l-reduction at the end.
// Block = 4 waves x 32 q = 128 q; grid 512; XCD remap groups the 16 blocks of
// one (b,h) on one XCD for K/V L2 residency.
// ---------------------------------------------------------------------------
__global__ __launch_bounds__(256)
void attn_kernel(const unsigned short* __restrict__ Qb,
                 const unsigned short* __restrict__ Kb,
                 const unsigned short* __restrict__ Vt,
                 unsigned short* __restrict__ Ap)
{
    __shared__ unsigned short sK[2][64*64];    // 2 x 8 KB, XOR-swizzled rows
    __shared__ unsigned short sV[2][64*64];    // 2 x 8 KB
    __shared__ unsigned int   sPT[4][32*36];   // per-wave P^T hop, 144B rows

    const int tid = threadIdx.x, lane = tid & 63, w4 = tid >> 6;
    const int m16 = lane & 15, q4 = lane >> 4;

    int id = blockIdx.x;                 // 0..511
    int xcd = id & 7, jj = id >> 3;      // jj 0..63
    const int bh = xcd * 4 + (jj >> 4);  // 4 heads per XCD
    const int qc = jj & 15;
    const int b = bh >> 4, h = bh & 15;
    const int qw = qc * 128 + w4 * 32;

    const unsigned short* Qp = Qb + (size_t)bh * (S_LEN * HD);
    const unsigned short* Kp = Kb + (size_t)bh * (S_LEN * HD);
    const unsigned short* Vp = Vt + (size_t)bh * (S_LEN * HD);
    unsigned int* pw = sPT[w4];

    // Q B-fragments (fixed for whole kernel): [n=q=lane&15][k=d]
    bfrag aq[2][2];
    #pragma unroll
    for (int nt = 0; nt < 2; nt++)
        #pragma unroll
        for (int kc = 0; kc < 2; kc++)
            aq[nt][kc] = *(const bfrag*)&Qp[(size_t)(qw + nt*16 + m16) * HD + kc*32 + q4*8];

    // staging: 512 granules (16B) per matrix, 2 async16 per thread per matrix.
    // granule G: row r = G>>3, src col-granule g = (G&7)^(r&7) (XOR swizzle).
    const int r0 = tid >> 3,         g0 = (tid & 7) ^ (r0 & 7);
    const int r1 = (tid + 256) >> 3, g1 = (tid & 7) ^ (r1 & 7);
    const char* gK0 = (const char*)Kp + (size_t)r0 * 128  + g0 * 16;  // + tile*8192
    const char* gK1 = (const char*)Kp + (size_t)r1 * 128  + g1 * 16;
    const char* gV0 = (const char*)Vp + (size_t)r0 * 4096 + g0 * 16;  // + tile*128
    const char* gV1 = (const char*)Vp + (size_t)r1 * 4096 + g1 * 16;
    const int ldsw = w4 * 1024;          // per-wave LDS byte base within a call

    const f32x4 zero4 = {0.f, 0.f, 0.f, 0.f};
    f32x4 O[2][4];
    float lp[2] = {0.f, 0.f};
    #pragma unroll
    for (int nt = 0; nt < 2; nt++)
        #pragma unroll
        for (int dt = 0; dt < 4; dt++) O[nt][dt] = zero4;

    // prefetch tile 0 into buffer 0
    async16((char*)sK[0] + ldsw,        gK0);
    async16((char*)sK[0] + 4096 + ldsw, gK1);
    async16((char*)sV[0] + ldsw,        gV0);
    async16((char*)sV[0] + 4096 + ldsw, gV1);

    const int NT = S_LEN / 64;
    for (int it = 0; it < NT; it++) {
        const int bi = it & 1;
        __syncthreads();   // drains async (cur tile ready) + prior compute done
        if (it + 1 < NT) {
            size_t ko = (size_t)(it + 1) * 8192, vo = (size_t)(it + 1) * 128;
            async16((char*)sK[bi^1] + ldsw,        gK0 + ko);
            async16((char*)sK[bi^1] + 4096 + ldsw, gK1 + ko);
            async16((char*)sV[bi^1] + ldsw,        gV0 + vo);
            async16((char*)sV[bi^1] + 4096 + ldsw, gV1 + vo);
        }

        const unsigned short* kb = sK[bi];
        const unsigned short* vb = sV[bi];

        // K A-frags [m=t][k=d] from swizzled LDS
        bfrag ak[4][2];
        #pragma unroll
        for (int mt = 0; mt < 4; mt++) {
            int r = mt*16 + m16, s = r & 7;
            ak[mt][0] = *(const bfrag*)&kb[r*64 + ((q4     ^ s) << 3)];
            ak[mt][1] = *(const bfrag*)&kb[r*64 + (((4+q4) ^ s) << 3)];
        }

        // S^T = K.Q^T, then p = exp2(s), round-half-up to bf16, stash P^T rows;
        // l accumulates the SAME rounded values PV will consume.
        #pragma unroll
        for (int nt = 0; nt < 2; nt++) {
            f32x4 Sc[4];
            #pragma unroll
            for (int mt = 0; mt < 4; mt++) {
                Sc[mt] = mfma16(ak[mt][0], aq[nt][0], zero4);
                Sc[mt] = mfma16(ak[mt][1], aq[nt][1], Sc[mt]);
            }
            unsigned rowb = (unsigned)(nt*16 + m16) * 36;
            #pragma unroll
            for (int mt = 0; mt < 4; mt++) {
                float p0 = EXP2F(Sc[mt][0]), p1 = EXP2F(Sc[mt][1]);
                float p2 = EXP2F(Sc[mt][2]), p3 = EXP2F(Sc[mt][3]);
                unsigned c0 = pack_rhu(p0, p1);
                unsigned c1 = pack_rhu(p2, p3);
                float u0 = __builtin_bit_cast(float, c0 << 16);
                float u1 = __builtin_bit_cast(float, c0 & 0xffff0000u);
                float u2 = __builtin_bit_cast(float, c1 << 16);
                float u3 = __builtin_bit_cast(float, c1 & 0xffff0000u);
                lp[nt] += (u0 + u1) + (u2 + u3);
                uint2 c2 = { c0, c1 };
                *(uint2*)&pw[rowb + mt*8 + q4*2] = c2;
            }
        }

        // V^T A-frags [m=d][k=t] from swizzled LDS
        bfrag av[4][2];
        #pragma unroll
        for (int dt = 0; dt < 4; dt++) {
            int r = dt*16 + m16, s = r & 7;
            av[dt][0] = *(const bfrag*)&vb[r*64 + ((q4     ^ s) << 3)];
            av[dt][1] = *(const bfrag*)&vb[r*64 + (((4+q4) ^ s) << 3)];
        }

        // O^T += V^T . P^T  (P^T B-frags: [n=q=lane&15][k=t=quad*8+j])
        #pragma unroll
        for (int nt = 0; nt < 2; nt++) {
            bfrag bp[2];
            #pragma unroll
            for (int kc = 0; kc < 2; kc++)
                bp[kc] = __builtin_bit_cast(bfrag,
                    *(const i32x4_t*)&pw[(unsigned)(nt*16 + m16) * 36 + kc*16 + q4*4]);
            #pragma unroll
            for (int dt = 0; dt < 4; dt++) {
                O[nt][dt] = mfma16(av[dt][0], bp[0], O[nt][dt]);
                O[nt][dt] = mfma16(av[dt][1], bp[1], O[nt][dt]);
            }
        }
    }

    // epilogue: reduce l over the 4 quad-lanes holding the same q, normalize,
    // write RN bf16 attn plane [r = s*2+b][h*64+d]
    #pragma unroll
    for (int nt = 0; nt < 2; nt++) {
        float l = lp[nt];
        l += __shfl_xor(l, 16);
        l += __shfl_xor(l, 32);
        float inv = 1.0f / l;
        int q = qw + nt*16 + m16;
        size_t rb = ((size_t)q * BATCH + b) * DM + h * 64;
        #pragma unroll
        for (int dt = 0; dt < 4; dt++) {
            u16x4_t o = { bf16_rn(O[nt][dt][0] * inv), bf16_rn(O[nt][dt][1] * inv),
                          bf16_rn(O[nt][dt][2] * inv), bf16_rn(O[nt][dt][3] * inv) };
            *(u16x4_t*)&Ap[rb + dt*16 + q4*4] = o;
        }
    }
}

// ---------------------------------------------------------------------------
// Out projection: d_out = attn @ Wo^T + bo (fp32). 2-phase split on W:
// acc = A.Wh + A.Wl (A = RN-bf16 attn plane; dropped Al.Wh term is ~2.5e-4).
// All staging via global_load_lds. 128x128 tile, BK=32, 8 waves. XCD remap.
// ---------------------------------------------------------------------------
__global__ __launch_bounds__(512)
void out_gemm(const unsigned short* __restrict__ Ap,
              const unsigned short* __restrict__ Woh,
              const unsigned short* __restrict__ Wol,
              const float* __restrict__ bo, float* __restrict__ out)
{
    __shared__ unsigned short sA[128*32];
    __shared__ unsigned short sH[128*32];
    __shared__ unsigned short sL[128*32];

    const int tid = threadIdx.x, lane = tid & 63, w8 = tid >> 6;
    const int m16 = lane & 15, q4 = lane >> 4;
    const int wr = w8 >> 2, wc = w8 & 3;

    int id = blockIdx.x + 8 * blockIdx.y;
    int j  = id >> 3;
    const int m0 = ((id & 7) * 4 + (j & 3)) * 128;
    const int n0 = (j >> 2) * 128;

    const int br = tid >> 2,  bc = (tid & 3) ^ ((br ^ (br >> 2)) & 3);
    const unsigned short* gA = Ap  + (size_t)(m0 + br) * DM + bc * 8;
    const unsigned short* gH = Woh + (size_t)(n0 + br) * DM + bc * 8;
    const unsigned short* gL = Wol + (size_t)(n0 + br) * DM + bc * 8;
    unsigned short* ldsA = &sA[w8 * 512];
    unsigned short* ldsH = &sH[w8 * 512];
    unsigned short* ldsL = &sL[w8 * 512];

    int offA[4], offB[2];
    #pragma unroll
    for (int rt = 0; rt < 4; rt++) {
        int r = wr * 64 + rt * 16 + m16;
        offA[rt] = r * 32 + ((q4 ^ ((r ^ (r >> 2)) & 3)) << 3);
    }
    #pragma unroll
    for (int ct = 0; ct < 2; ct++) {
        int r = wc * 32 + ct * 16 + m16;
        offB[ct] = r * 32 + ((q4 ^ ((r ^ (r >> 2)) & 3)) << 3);
    }

    f32x4 acc[4][2];
    const f32x4 zero4 = {0.f, 0.f, 0.f, 0.f};
    #pragma unroll
    for (int i = 0; i < 4; i++)
        #pragma unroll
        for (int jj = 0; jj < 2; jj++) acc[i][jj] = zero4;

    for (int k0 = 0; k0 < DM; k0 += 32) {
        async16(ldsA, gA);
        async16(ldsH, gH);
        async16(ldsL, gL);
        gA += 32; gH += 32; gL += 32;
        __syncthreads();

        bfrag a[4], bh2[2], bl2[2];
        #pragma unroll
        for (int rt = 0; rt < 4; rt++) a[rt] = *(const bfrag*)&sA[offA[rt]];
        #pragma unroll
        for (int ct = 0; ct < 2; ct++) {
            bh2[ct] = *(const bfrag*)&sH[offB[ct]];
            bl2[ct] = *(const bfrag*)&sL[offB[ct]];
        }
        #pragma unroll
        for (int rt = 0; rt < 4; rt++)
            #pragma unroll
            for (int ct = 0; ct < 2; ct++) {
                acc[rt][ct] = mfma16(a[rt], bh2[ct], acc[rt][ct]);
                acc[rt][ct] = mfma16(a[rt], bl2[ct], acc[rt][ct]);
            }
        __syncthreads();
    }

    #pragma unroll
    for (int rt = 0; rt < 4; rt++)
        #pragma unroll
        for (int ct = 0; ct < 2; ct++)
            #pragma unroll
            for (int reg = 0; reg < 4; reg++) {
                int r = m0 + wr * 64 + rt * 16 + q4 * 4 + reg;
                int c = n0 + wc * 32 + ct * 16 + m16;
                out[(size_t)r * DM + c] = acc[rt][ct][reg] + bo[c];
            }
}

// ---------------------------------------------------------------------------
extern "C" void kernel_launch(void* const* d_in, const int* in_sizes, int n_in,
                              void* d_out, int out_size, void* d_ws, size_t ws_size,
                              hipStream_t stream)
{
    const float* query = (const float*)d_in[0];
    const float* key   = (const float*)d_in[1];
    const float* value = (const float*)d_in[2];
    const float* Wq    = (const float*)d_in[3];
    const float* bq    = (const float*)d_in[4];
    const float* Wk    = (const float*)d_in[5];
    const float* bk    = (const float*)d_in[6];
    const float* Wv    = (const float*)d_in[7];
    const float* bv    = (const float*)d_in[8];
    const float* Wo    = (const float*)d_in[9];
    const float* bo    = (const float*)d_in[10];

    char* ws = (char*)d_ws;
    const size_t MB = 1u << 20;
    unsigned short* Qb  = (unsigned short*)(ws);            //  0..8 MB
    unsigned short* Kb  = (unsigned short*)(ws +  8*MB);    //  8..16
    unsigned short* Vt  = (unsigned short*)(ws + 16*MB);    // 16..24
    unsigned short* Woh = (unsigned short*)(ws + 24*MB);    // 24..26 (live till out_gemm)
    unsigned short* Wol = (unsigned short*)(ws + 26*MB);    // 26..28
    unsigned short* Wqb = (unsigned short*)(ws + 28*MB);    // 28..30 (dead after qkv)
    unsigned short* Wkb = (unsigned short*)(ws + 30*MB);    // 30..32
    unsigned short* Wvb = (unsigned short*)(ws + 32*MB);    // 32..34
    unsigned short* Ap  = (unsigned short*)(ws + 28*MB);    // 28..36, aliases Wqb/Wkb/Wvb
    // peak footprint: 36 MB (<= validated 40 MB)

    cvt_kernel<<<dim3(512, 1, 4), 256, 0, stream>>>(
        Wq, Wk, Wv, Wo, Wqb, Wkb, Wvb, Woh, Wol);
    qkv_gemm<<<dim3(8, 32, 3), 512, 0, stream>>>(
        query, key, value, Wqb, Wkb, Wvb, bq, bk, bv, Qb, Kb, Vt);
    attn_kernel<<<dim3(512), 256, 0, stream>>>(Qb, Kb, Vt, Ap);
    out_gemm<<<dim3(8, 32), 512, 0, stream>>>(Ap, Woh, Wol, bo, (float*)d_out);
}

// Round 7
// 243.784 us; speedup vs baseline: 1.2921x; 1.0512x over previous
//
#include <hip/hip_runtime.h>
#include <stdint.h>

// Problem constants (MultiHeadAttention: S=2048, B=2, D=1024, H=16, Hd=64)
#define S_LEN 2048
#define BATCH 2
#define DM    1024
#define NH    16
#define HD    64
#define MROWS 4096            // GEMM rows, r = s*2 + b

typedef float f32x4 __attribute__((ext_vector_type(4)));
typedef short bfrag __attribute__((ext_vector_type(8)));   // 8 bf16 bit patterns (4 VGPRs)
typedef unsigned short u16x4_t __attribute__((ext_vector_type(4)));
typedef unsigned short u16x8_t __attribute__((ext_vector_type(8)));
typedef int i32x4_t __attribute__((ext_vector_type(4)));

#define EXP2F(x) __builtin_amdgcn_exp2f(x)

__device__ inline f32x4 mfma16(bfrag a, bfrag b, f32x4 c) {
    return __builtin_amdgcn_mfma_f32_16x16x32_bf16(a, b, c, 0, 0, 0);
}

// round-to-nearest-even-ish f32 -> bf16 bits
__device__ inline unsigned short bf16_rn(float x) {
    unsigned u = __builtin_bit_cast(unsigned, x);
    return (unsigned short)((u + 0x7fffu + ((u >> 16) & 1u)) >> 16);
}

// truncating hi/lo split: x ~= hi + lo with ~17 mantissa bits captured
__device__ inline void split_bf16(float x, unsigned short &h, unsigned short &l) {
    unsigned u = __builtin_bit_cast(unsigned, x);
    h = (unsigned short)(u >> 16);
    float hf = __builtin_bit_cast(float, u & 0xffff0000u);
    float r = x - hf;
    l = (unsigned short)(__builtin_bit_cast(unsigned, r) >> 16);
}

// pack two fp32 into two ROUND-HALF-UP bf16 in one b32 (lo = a, hi = b).
__device__ inline unsigned pack_rhu(float a, float b) {
    unsigned ua = __builtin_bit_cast(unsigned, a) + 0x8000u;
    unsigned ub = __builtin_bit_cast(unsigned, b) + 0x8000u;
    return (ua >> 16) | (ub & 0xffff0000u);
}

// async global->LDS, 16B per lane; lds must be wave-uniform base (lane*16 implicit)
typedef __attribute__((address_space(1))) const unsigned int as1_u32;
typedef __attribute__((address_space(3))) unsigned int as3_u32;
__device__ inline void async16(void* lds, const void* g) {
    __builtin_amdgcn_global_load_lds((as1_u32*)g, (as3_u32*)lds, 16, 0, 0);
}

// ---------------------------------------------------------------------------
// Conversion pass: z=0..2 Wq/Wk/Wv -> bf16; z=3 Wo -> hi/lo planes;
// z=4..6 query/key/value -> bf16 A-planes (hoists the fp32->bf16 conversion
// out of qkv_gemm's k-loop, where it was 16x-redundant and VALU-bound).
// ---------------------------------------------------------------------------
__global__ __launch_bounds__(256)
void cvt_kernel(const float* __restrict__ Wq, const float* __restrict__ Wk,
                const float* __restrict__ Wv, const float* __restrict__ Wo,
                const float* __restrict__ Qin, const float* __restrict__ Kin,
                const float* __restrict__ Vin,
                unsigned short* __restrict__ Wqb, unsigned short* __restrict__ Wkb,
                unsigned short* __restrict__ Wvb,
                unsigned short* __restrict__ Woh, unsigned short* __restrict__ Wol,
                unsigned short* __restrict__ Qa,  unsigned short* __restrict__ Ka,
                unsigned short* __restrict__ Va)
{
    const int z = blockIdx.z;
    size_t idx = ((size_t)blockIdx.x * 256 + threadIdx.x) * 8;
    const size_t limit = (z < 4) ? (size_t)DM * DM : (size_t)MROWS * DM;
    if (idx >= limit) return;
    const float* src = (z == 0) ? Wq : (z == 1) ? Wk : (z == 2) ? Wv :
                       (z == 3) ? Wo : (z == 4) ? Qin : (z == 5) ? Kin : Vin;
    float4 f0 = *(const float4*)&src[idx];
    float4 f1 = *(const float4*)&src[idx + 4];
    if (z != 3) {
        unsigned short* dst = (z == 0) ? Wqb : (z == 1) ? Wkb : (z == 2) ? Wvb :
                              (z == 4) ? Qa  : (z == 5) ? Ka  : Va;
        u16x8_t v = { bf16_rn(f0.x), bf16_rn(f0.y), bf16_rn(f0.z), bf16_rn(f0.w),
                      bf16_rn(f1.x), bf16_rn(f1.y), bf16_rn(f1.z), bf16_rn(f1.w) };
        *(u16x8_t*)&dst[idx] = v;
    } else {
        unsigned short h0,h1,h2,h3,h4,h5,h6,h7, l0,l1,l2,l3,l4,l5,l6,l7;
        split_bf16(f0.x,h0,l0); split_bf16(f0.y,h1,l1);
        split_bf16(f0.z,h2,l2); split_bf16(f0.w,h3,l3);
        split_bf16(f1.x,h4,l4); split_bf16(f1.y,h5,l5);
        split_bf16(f1.z,h6,l6); split_bf16(f1.w,h7,l7);
        u16x8_t vh = {h0,h1,h2,h3,h4,h5,h6,h7};
        u16x8_t vl = {l0,l1,l2,l3,l4,l5,l6,l7};
        *(u16x8_t*)&Woh[idx] = vh;
        *(u16x8_t*)&Wol[idx] = vl;
    }
}

// ---------------------------------------------------------------------------
// Q/K/V projection, verified m97 shape: 256 threads, 4 waves in 2x2, each
// wave 64x64 (4x4 acc, 16 MFMA per 8 ds_read_b128 per k-iter), pure bf16,
// A and W staged via global_load_lds (16B, XOR-swizzled slots).
// XCD remap: id%8 selects an M-strip of 4 row-blocks (A L2 locality).
// z=0: Q (scale log2e/8) -> [b][h][s][d]; z=1: K -> same; z=2: V -> [b][h][d][s]
// ---------------------------------------------------------------------------
__global__ __launch_bounds__(256)
void qkv_gemm(const unsigned short* __restrict__ Qa,
              const unsigned short* __restrict__ Ka,
              const unsigned short* __restrict__ Va,
              const unsigned short* __restrict__ Wqb,
              const unsigned short* __restrict__ Wkb,
              const unsigned short* __restrict__ Wvb,
              const float* __restrict__ bq, const float* __restrict__ bk,
              const float* __restrict__ bv,
              unsigned short* __restrict__ Qb, unsigned short* __restrict__ Kb,
              unsigned short* __restrict__ Vt)
{
    __shared__ unsigned short sA[128*32];   // 8 KB bf16 A tile
    __shared__ unsigned short sB[128*32];   // 8 KB bf16 W tile

    const int tid = threadIdx.x, lane = tid & 63, w4 = tid >> 6;
    const int m16 = lane & 15, q4 = lane >> 4;
    const int wr = w4 >> 1, wc = w4 & 1;   // 2x2 wave grid -> 64x64 per wave
    const int z = blockIdx.z;

    // XCD-aware remap (256 blocks per z): XCD = id%8 owns M-strip of 4 blocks
    int id = blockIdx.x + 8 * blockIdx.y;
    int j  = id >> 3;
    const int m0 = ((id & 7) * 4 + (j & 3)) * 128;
    const int n0 = (j >> 2) * 128;

    const unsigned short* A = (z == 0) ? Qa : (z == 1) ? Ka : Va;
    const unsigned short* W = (z == 0) ? Wqb : (z == 1) ? Wkb : Wvb;
    const float* bias = (z == 0) ? bq : (z == 1) ? bk : bv;
    unsigned short* outp = (z == 0) ? Qb : (z == 1) ? Kb : Vt;

    // staging: 512 granules (16B = 8 bf16) per matrix, 2 per thread per matrix.
    // granule G: row r = G>>2, slot = G&3 holds source col-granule (G&3)^swz(r),
    // swz(r) = (r^(r>>2))&3  (same pattern as out_gemm).
    const int G1 = tid + 256;
    const int r0 = tid >> 2, g0 = (tid & 3) ^ ((r0 ^ (r0 >> 2)) & 3);
    const int r1 = G1  >> 2, g1 = (G1  & 3) ^ ((r1 ^ (r1 >> 2)) & 3);
    const char* gA0 = (const char*)A + (size_t)(m0 + r0) * 2048 + g0 * 16;
    const char* gA1 = (const char*)A + (size_t)(m0 + r1) * 2048 + g1 * 16;
    const char* gB0 = (const char*)W + (size_t)(n0 + r0) * 2048 + g0 * 16;
    const char* gB1 = (const char*)W + (size_t)(n0 + r1) * 2048 + g1 * 16;
    char* ldsA0 = (char*)sA + w4 * 1024;
    char* ldsA1 = (char*)sA + 4096 + w4 * 1024;
    char* ldsB0 = (char*)sB + w4 * 1024;
    char* ldsB1 = (char*)sB + 4096 + w4 * 1024;

    // fragment LDS offsets (u16 units), loop-invariant
    int offA[4], offB[4];
    #pragma unroll
    for (int rt = 0; rt < 4; rt++) {
        int r = wr * 64 + rt * 16 + m16;
        offA[rt] = r * 32 + ((q4 ^ ((r ^ (r >> 2)) & 3)) << 3);
    }
    #pragma unroll
    for (int ct = 0; ct < 4; ct++) {
        int r = wc * 64 + ct * 16 + m16;
        offB[ct] = r * 32 + ((q4 ^ ((r ^ (r >> 2)) & 3)) << 3);
    }

    f32x4 acc[4][4];
    const f32x4 zero4 = {0.f, 0.f, 0.f, 0.f};
    #pragma unroll
    for (int i = 0; i < 4; i++)
        #pragma unroll
        for (int jj = 0; jj < 4; jj++) acc[i][jj] = zero4;

    for (int k0 = 0; k0 < DM; k0 += 32) {
        async16(ldsA0, gA0);
        async16(ldsA1, gA1);
        async16(ldsB0, gB0);
        async16(ldsB1, gB1);
        gA0 += 64; gA1 += 64; gB0 += 64; gB1 += 64;
        __syncthreads();

        bfrag a[4], bb[4];
        #pragma unroll
        for (int rt = 0; rt < 4; rt++) a[rt]  = *(const bfrag*)&sA[offA[rt]];
        #pragma unroll
        for (int ct = 0; ct < 4; ct++) bb[ct] = *(const bfrag*)&sB[offB[ct]];

        #pragma unroll
        for (int rt = 0; rt < 4; rt++)
            #pragma unroll
            for (int ct = 0; ct < 4; ct++)
                acc[rt][ct] = mfma16(a[rt], bb[ct], acc[rt][ct]);
        __syncthreads();
    }

    const float SCALE = (z == 0) ? 0.18033688011112042f : 1.0f; // log2(e)/8
    #pragma unroll
    for (int rt = 0; rt < 4; rt++)
        #pragma unroll
        for (int ct = 0; ct < 4; ct++)
            #pragma unroll
            for (int reg = 0; reg < 4; reg++) {
                int r = m0 + wr * 64 + rt * 16 + q4 * 4 + reg;
                int c = n0 + wc * 64 + ct * 16 + m16;
                float v = (acc[rt][ct][reg] + bias[c]) * SCALE;
                int s = r >> 1, b = r & 1, hh = c >> 6, d = c & 63;
                unsigned short bv16 = bf16_rn(v);
                if (z == 2)
                    outp[((size_t)(b * NH + hh) * HD + d) * S_LEN + s] = bv16;
                else
                    outp[((size_t)(b * NH + hh) * S_LEN + s) * HD + d] = bv16;
            }
}

// ---------------------------------------------------------------------------
// Attention, transposed orientation, LDS-staged + double-buffered K/V
// (unchanged from R6: dropped attn from 126 us to < 74 us).
// ---------------------------------------------------------------------------
__global__ __launch_bounds__(256)
void attn_kernel(const unsigned short* __restrict__ Qb,
                 const unsigned short* __restrict__ Kb,
                 const unsigned short* __restrict__ Vt,
                 unsigned short* __restrict__ Ap)
{
    __shared__ unsigned short sK[2][64*64];    // 2 x 8 KB, XOR-swizzled rows
    __shared__ unsigned short sV[2][64*64];    // 2 x 8 KB
    __shared__ unsigned int   sPT[4][32*36];   // per-wave P^T hop, 144B rows

    const int tid = threadIdx.x, lane = tid & 63, w4 = tid >> 6;
    const int m16 = lane & 15, q4 = lane >> 4;

    int id = blockIdx.x;                 // 0..511
    int xcd = id & 7, jj = id >> 3;      // jj 0..63
    const int bh = xcd * 4 + (jj >> 4);  // 4 heads per XCD
    const int qc = jj & 15;
    const int b = bh >> 4, h = bh & 15;
    const int qw = qc * 128 + w4 * 32;

    const unsigned short* Qp = Qb + (size_t)bh * (S_LEN * HD);
    const unsigned short* Kp = Kb + (size_t)bh * (S_LEN * HD);
    const unsigned short* Vp = Vt + (size_t)bh * (S_LEN * HD);
    unsigned int* pw = sPT[w4];

    // Q B-fragments (fixed for whole kernel): [n=q=lane&15][k=d]
    bfrag aq[2][2];
    #pragma unroll
    for (int nt = 0; nt < 2; nt++)
        #pragma unroll
        for (int kc = 0; kc < 2; kc++)
            aq[nt][kc] = *(const bfrag*)&Qp[(size_t)(qw + nt*16 + m16) * HD + kc*32 + q4*8];

    // staging: 512 granules (16B) per matrix, 2 async16 per thread per matrix.
    const int r0 = tid >> 3,         g0 = (tid & 7) ^ (r0 & 7);
    const int r1 = (tid + 256) >> 3, g1 = (tid & 7) ^ (r1 & 7);
    const char* gK0 = (const char*)Kp + (size_t)r0 * 128  + g0 * 16;  // + tile*8192
    const char* gK1 = (const char*)Kp + (size_t)r1 * 128  + g1 * 16;
    const char* gV0 = (const char*)Vp + (size_t)r0 * 4096 + g0 * 16;  // + tile*128
    const char* gV1 = (const char*)Vp + (size_t)r1 * 4096 + g1 * 16;
    const int ldsw = w4 * 1024;          // per-wave LDS byte base within a call

    const f32x4 zero4 = {0.f, 0.f, 0.f, 0.f};
    f32x4 O[2][4];
    float lp[2] = {0.f, 0.f};
    #pragma unroll
    for (int nt = 0; nt < 2; nt++)
        #pragma unroll
        for (int dt = 0; dt < 4; dt++) O[nt][dt] = zero4;

    // prefetch tile 0 into buffer 0
    async16((char*)sK[0] + ldsw,        gK0);
    async16((char*)sK[0] + 4096 + ldsw, gK1);
    async16((char*)sV[0] + ldsw,        gV0);
    async16((char*)sV[0] + 4096 + ldsw, gV1);

    const int NT = S_LEN / 64;
    for (int it = 0; it < NT; it++) {
        const int bi = it & 1;
        __syncthreads();   // drains async (cur tile ready) + prior compute done
        if (it + 1 < NT) {
            size_t ko = (size_t)(it + 1) * 8192, vo = (size_t)(it + 1) * 128;
            async16((char*)sK[bi^1] + ldsw,        gK0 + ko);
            async16((char*)sK[bi^1] + 4096 + ldsw, gK1 + ko);
            async16((char*)sV[bi^1] + ldsw,        gV0 + vo);
            async16((char*)sV[bi^1] + 4096 + ldsw, gV1 + vo);
        }

        const unsigned short* kb = sK[bi];
        const unsigned short* vb = sV[bi];

        // K A-frags [m=t][k=d] from swizzled LDS
        bfrag ak[4][2];
        #pragma unroll
        for (int mt = 0; mt < 4; mt++) {
            int r = mt*16 + m16, s = r & 7;
            ak[mt][0] = *(const bfrag*)&kb[r*64 + ((q4     ^ s) << 3)];
            ak[mt][1] = *(const bfrag*)&kb[r*64 + (((4+q4) ^ s) << 3)];
        }

        // S^T = K.Q^T, then p = exp2(s), round-half-up to bf16, stash P^T rows;
        // l accumulates the SAME rounded values PV will consume.
        #pragma unroll
        for (int nt = 0; nt < 2; nt++) {
            f32x4 Sc[4];
            #pragma unroll
            for (int mt = 0; mt < 4; mt++) {
                Sc[mt] = mfma16(ak[mt][0], aq[nt][0], zero4);
                Sc[mt] = mfma16(ak[mt][1], aq[nt][1], Sc[mt]);
            }
            unsigned rowb = (unsigned)(nt*16 + m16) * 36;
            #pragma unroll
            for (int mt = 0; mt < 4; mt++) {
                float p0 = EXP2F(Sc[mt][0]), p1 = EXP2F(Sc[mt][1]);
                float p2 = EXP2F(Sc[mt][2]), p3 = EXP2F(Sc[mt][3]);
                unsigned c0 = pack_rhu(p0, p1);
                unsigned c1 = pack_rhu(p2, p3);
                float u0 = __builtin_bit_cast(float, c0 << 16);
                float u1 = __builtin_bit_cast(float, c0 & 0xffff0000u);
                float u2 = __builtin_bit_cast(float, c1 << 16);
                float u3 = __builtin_bit_cast(float, c1 & 0xffff0000u);
                lp[nt] += (u0 + u1) + (u2 + u3);
                uint2 c2 = { c0, c1 };
                *(uint2*)&pw[rowb + mt*8 + q4*2] = c2;
            }
        }

        // V^T A-frags [m=d][k=t] from swizzled LDS
        bfrag av[4][2];
        #pragma unroll
        for (int dt = 0; dt < 4; dt++) {
            int r = dt*16 + m16, s = r & 7;
            av[dt][0] = *(const bfrag*)&vb[r*64 + ((q4     ^ s) << 3)];
            av[dt][1] = *(const bfrag*)&vb[r*64 + (((4+q4) ^ s) << 3)];
        }

        // O^T += V^T . P^T  (P^T B-frags: [n=q=lane&15][k=t=quad*8+j])
        #pragma unroll
        for (int nt = 0; nt < 2; nt++) {
            bfrag bp[2];
            #pragma unroll
            for (int kc = 0; kc < 2; kc++)
                bp[kc] = __builtin_bit_cast(bfrag,
                    *(const i32x4_t*)&pw[(unsigned)(nt*16 + m16) * 36 + kc*16 + q4*4]);
            #pragma unroll
            for (int dt = 0; dt < 4; dt++) {
                O[nt][dt] = mfma16(av[dt][0], bp[0], O[nt][dt]);
                O[nt][dt] = mfma16(av[dt][1], bp[1], O[nt][dt]);
            }
        }
    }

    // epilogue: reduce l over the 4 quad-lanes holding the same q, normalize,
    // write RN bf16 attn plane [r = s*2+b][h*64+d]
    #pragma unroll
    for (int nt = 0; nt < 2; nt++) {
        float l = lp[nt];
        l += __shfl_xor(l, 16);
        l += __shfl_xor(l, 32);
        float inv = 1.0f / l;
        int q = qw + nt*16 + m16;
        size_t rb = ((size_t)q * BATCH + b) * DM + h * 64;
        #pragma unroll
        for (int dt = 0; dt < 4; dt++) {
            u16x4_t o = { bf16_rn(O[nt][dt][0] * inv), bf16_rn(O[nt][dt][1] * inv),
                          bf16_rn(O[nt][dt][2] * inv), bf16_rn(O[nt][dt][3] * inv) };
            *(u16x4_t*)&Ap[rb + dt*16 + q4*4] = o;
        }
    }
}

// ---------------------------------------------------------------------------
// Out projection: d_out = attn @ Wo^T + bo (fp32). 2-phase split on W:
// acc = A.Wh + A.Wl (A = RN-bf16 attn plane; dropped Al.Wh term is ~2.5e-4).
// All staging via global_load_lds. 128x128 tile, BK=32, 8 waves. XCD remap.
// ---------------------------------------------------------------------------
__global__ __launch_bounds__(512)
void out_gemm(const unsigned short* __restrict__ Ap,
              const unsigned short* __restrict__ Woh,
              const unsigned short* __restrict__ Wol,
              const float* __restrict__ bo, float* __restrict__ out)
{
    __shared__ unsigned short sA[128*32];
    __shared__ unsigned short sH[128*32];
    __shared__ unsigned short sL[128*32];

    const int tid = threadIdx.x, lane = tid & 63, w8 = tid >> 6;
    const int m16 = lane & 15, q4 = lane >> 4;
    const int wr = w8 >> 2, wc = w8 & 3;

    int id = blockIdx.x + 8 * blockIdx.y;
    int j  = id >> 3;
    const int m0 = ((id & 7) * 4 + (j & 3)) * 128;
    const int n0 = (j >> 2) * 128;

    const int br = tid >> 2,  bc = (tid & 3) ^ ((br ^ (br >> 2)) & 3);
    const unsigned short* gA = Ap  + (size_t)(m0 + br) * DM + bc * 8;
    const unsigned short* gH = Woh + (size_t)(n0 + br) * DM + bc * 8;
    const unsigned short* gL = Wol + (size_t)(n0 + br) * DM + bc * 8;
    unsigned short* ldsA = &sA[w8 * 512];
    unsigned short* ldsH = &sH[w8 * 512];
    unsigned short* ldsL = &sL[w8 * 512];

    int offA[4], offB[2];
    #pragma unroll
    for (int rt = 0; rt < 4; rt++) {
        int r = wr * 64 + rt * 16 + m16;
        offA[rt] = r * 32 + ((q4 ^ ((r ^ (r >> 2)) & 3)) << 3);
    }
    #pragma unroll
    for (int ct = 0; ct < 2; ct++) {
        int r = wc * 32 + ct * 16 + m16;
        offB[ct] = r * 32 + ((q4 ^ ((r ^ (r >> 2)) & 3)) << 3);
    }

    f32x4 acc[4][2];
    const f32x4 zero4 = {0.f, 0.f, 0.f, 0.f};
    #pragma unroll
    for (int i = 0; i < 4; i++)
        #pragma unroll
        for (int jj = 0; jj < 2; jj++) acc[i][jj] = zero4;

    for (int k0 = 0; k0 < DM; k0 += 32) {
        async16(ldsA, gA);
        async16(ldsH, gH);
        async16(ldsL, gL);
        gA += 32; gH += 32; gL += 32;
        __syncthreads();

        bfrag a[4], bh2[2], bl2[2];
        #pragma unroll
        for (int rt = 0; rt < 4; rt++) a[rt] = *(const bfrag*)&sA[offA[rt]];
        #pragma unroll
        for (int ct = 0; ct < 2; ct++) {
            bh2[ct] = *(const bfrag*)&sH[offB[ct]];
            bl2[ct] = *(const bfrag*)&sL[offB[ct]];
        }
        #pragma unroll
        for (int rt = 0; rt < 4; rt++)
            #pragma unroll
            for (int ct = 0; ct < 2; ct++) {
                acc[rt][ct] = mfma16(a[rt], bh2[ct], acc[rt][ct]);
                acc[rt][ct] = mfma16(a[rt], bl2[ct], acc[rt][ct]);
            }
        __syncthreads();
    }

    #pragma unroll
    for (int rt = 0; rt < 4; rt++)
        #pragma unroll
        for (int ct = 0; ct < 2; ct++)
            #pragma unroll
            for (int reg = 0; reg < 4; reg++) {
                int r = m0 + wr * 64 + rt * 16 + q4 * 4 + reg;
                int c = n0 + wc * 32 + ct * 16 + m16;
                out[(size_t)r * DM + c] = acc[rt][ct][reg] + bo[c];
            }
}

// ---------------------------------------------------------------------------
extern "C" void kernel_launch(void* const* d_in, const int* in_sizes, int n_in,
                              void* d_out, int out_size, void* d_ws, size_t ws_size,
                              hipStream_t stream)
{
    const float* query = (const float*)d_in[0];
    const float* key   = (const float*)d_in[1];
    const float* value = (const float*)d_in[2];
    const float* Wq    = (const float*)d_in[3];
    const float* bq    = (const float*)d_in[4];
    const float* Wk    = (const float*)d_in[5];
    const float* bk    = (const float*)d_in[6];
    const float* Wv    = (const float*)d_in[7];
    const float* bv    = (const float*)d_in[8];
    const float* Wo    = (const float*)d_in[9];
    const float* bo    = (const float*)d_in[10];

    char* ws = (char*)d_ws;
    const size_t MB = 1u << 20;
    unsigned short* Qb  = (unsigned short*)(ws);            //  0..8 MB
    unsigned short* Kb  = (unsigned short*)(ws +  8*MB);    //  8..16
    unsigned short* Vt  = (unsigned short*)(ws + 16*MB);    // 16..24
    unsigned short* Woh = (unsigned short*)(ws + 24*MB);    // 24..26 (live till out_gemm)
    unsigned short* Wol = (unsigned short*)(ws + 26*MB);    // 26..28
    unsigned short* Wqb = (unsigned short*)(ws + 28*MB);    // 28..30 (dead after qkv)
    unsigned short* Wkb = (unsigned short*)(ws + 30*MB);    // 30..32
    unsigned short* Wvb = (unsigned short*)(ws + 32*MB);    // 32..34
    unsigned short* Va  = (unsigned short*)(ws + 34*MB);    // 34..42 (dead after qkv)
    unsigned short* Ap  = (unsigned short*)(ws + 28*MB);    // 28..36, written by attn
                                                            // after Wqb/Wkb/Wvb/Va die
    // Qa/Ka bf16 A-planes live in d_out (16 MB fp32): harness re-poisons d_out
    // before every launch; out_gemm writes the real output last.
    unsigned short* Qa  = (unsigned short*)d_out;           // d_out 0..8 MB
    unsigned short* Ka  = (unsigned short*)d_out + (size_t)MROWS*DM; // 8..16 MB
    // peak ws footprint: 42 MB

    cvt_kernel<<<dim3(2048, 1, 7), 256, 0, stream>>>(
        Wq, Wk, Wv, Wo, query, key, value,
        Wqb, Wkb, Wvb, Woh, Wol, Qa, Ka, Va);
    qkv_gemm<<<dim3(8, 32, 3), 256, 0, stream>>>(
        Qa, Ka, Va, Wqb, Wkb, Wvb, bq, bk, bv, Qb, Kb, Vt);
    attn_kernel<<<dim3(512), 256, 0, stream>>>(Qb, Kb, Vt, Ap);
    out_gemm<<<dim3(8, 32), 512, 0, stream>>>(Ap, Woh, Wol, bo, (float*)d_out);
}

// Round 8
// 238.847 us; speedup vs baseline: 1.3188x; 1.0207x over previous
//
#include <hip/hip_runtime.h>
#include <stdint.h>

// Problem constants (MultiHeadAttention: S=2048, B=2, D=1024, H=16, Hd=64)
#define S_LEN 2048
#define BATCH 2
#define DM    1024
#define NH    16
#define HD    64
#define MROWS 4096            // GEMM rows, r = s*2 + b

typedef float f32x4 __attribute__((ext_vector_type(4)));
typedef short bfrag __attribute__((ext_vector_type(8)));   // 8 bf16 bit patterns (4 VGPRs)
typedef unsigned short u16x4_t __attribute__((ext_vector_type(4)));
typedef unsigned short u16x8_t __attribute__((ext_vector_type(8)));
typedef int i32x4_t __attribute__((ext_vector_type(4)));

#define EXP2F(x) __builtin_amdgcn_exp2f(x)

__device__ inline f32x4 mfma16(bfrag a, bfrag b, f32x4 c) {
    return __builtin_amdgcn_mfma_f32_16x16x32_bf16(a, b, c, 0, 0, 0);
}

// round-to-nearest-even-ish f32 -> bf16 bits
__device__ inline unsigned short bf16_rn(float x) {
    unsigned u = __builtin_bit_cast(unsigned, x);
    return (unsigned short)((u + 0x7fffu + ((u >> 16) & 1u)) >> 16);
}

// truncating hi/lo split: x ~= hi + lo with ~17 mantissa bits captured
__device__ inline void split_bf16(float x, unsigned short &h, unsigned short &l) {
    unsigned u = __builtin_bit_cast(unsigned, x);
    h = (unsigned short)(u >> 16);
    float hf = __builtin_bit_cast(float, u & 0xffff0000u);
    float r = x - hf;
    l = (unsigned short)(__builtin_bit_cast(unsigned, r) >> 16);
}

// pack two fp32 into two ROUND-HALF-UP bf16 in one b32 (lo = a, hi = b).
__device__ inline unsigned pack_rhu(float a, float b) {
    unsigned ua = __builtin_bit_cast(unsigned, a) + 0x8000u;
    unsigned ub = __builtin_bit_cast(unsigned, b) + 0x8000u;
    return (ua >> 16) | (ub & 0xffff0000u);
}

// async global->LDS, 16B per lane; lds must be wave-uniform base (lane*16 implicit)
typedef __attribute__((address_space(1))) const unsigned int as1_u32;
typedef __attribute__((address_space(3))) unsigned int as3_u32;
__device__ inline void async16(void* lds, const void* g) {
    __builtin_amdgcn_global_load_lds((as1_u32*)g, (as3_u32*)lds, 16, 0, 0);
}

// ---------------------------------------------------------------------------
// Conversion pass: z=0..2 Wq/Wk/Wv -> bf16; z=3 Wo -> hi/lo planes;
// z=4..6 query/key/value -> bf16 A-planes.
// ---------------------------------------------------------------------------
__global__ __launch_bounds__(256)
void cvt_kernel(const float* __restrict__ Wq, const float* __restrict__ Wk,
                const float* __restrict__ Wv, const float* __restrict__ Wo,
                const float* __restrict__ Qin, const float* __restrict__ Kin,
                const float* __restrict__ Vin,
                unsigned short* __restrict__ Wqb, unsigned short* __restrict__ Wkb,
                unsigned short* __restrict__ Wvb,
                unsigned short* __restrict__ Woh, unsigned short* __restrict__ Wol,
                unsigned short* __restrict__ Qa,  unsigned short* __restrict__ Ka,
                unsigned short* __restrict__ Va)
{
    const int z = blockIdx.z;
    size_t idx = ((size_t)blockIdx.x * 256 + threadIdx.x) * 8;
    const size_t limit = (z < 4) ? (size_t)DM * DM : (size_t)MROWS * DM;
    if (idx >= limit) return;
    const float* src = (z == 0) ? Wq : (z == 1) ? Wk : (z == 2) ? Wv :
                       (z == 3) ? Wo : (z == 4) ? Qin : (z == 5) ? Kin : Vin;
    float4 f0 = *(const float4*)&src[idx];
    float4 f1 = *(const float4*)&src[idx + 4];
    if (z != 3) {
        unsigned short* dst = (z == 0) ? Wqb : (z == 1) ? Wkb : (z == 2) ? Wvb :
                              (z == 4) ? Qa  : (z == 5) ? Ka  : Va;
        u16x8_t v = { bf16_rn(f0.x), bf16_rn(f0.y), bf16_rn(f0.z), bf16_rn(f0.w),
                      bf16_rn(f1.x), bf16_rn(f1.y), bf16_rn(f1.z), bf16_rn(f1.w) };
        *(u16x8_t*)&dst[idx] = v;
    } else {
        unsigned short h0,h1,h2,h3,h4,h5,h6,h7, l0,l1,l2,l3,l4,l5,l6,l7;
        split_bf16(f0.x,h0,l0); split_bf16(f0.y,h1,l1);
        split_bf16(f0.z,h2,l2); split_bf16(f0.w,h3,l3);
        split_bf16(f1.x,h4,l4); split_bf16(f1.y,h5,l5);
        split_bf16(f1.z,h6,l6); split_bf16(f1.w,h7,l7);
        u16x8_t vh = {h0,h1,h2,h3,h4,h5,h6,h7};
        u16x8_t vl = {l0,l1,l2,l3,l4,l5,l6,l7};
        *(u16x8_t*)&Woh[idx] = vh;
        *(u16x8_t*)&Wol[idx] = vl;
    }
}

// ---------------------------------------------------------------------------
// Q/K/V projection, verified m97 shape (unchanged from R7: qkv left top-5).
// ---------------------------------------------------------------------------
__global__ __launch_bounds__(256)
void qkv_gemm(const unsigned short* __restrict__ Qa,
              const unsigned short* __restrict__ Ka,
              const unsigned short* __restrict__ Va,
              const unsigned short* __restrict__ Wqb,
              const unsigned short* __restrict__ Wkb,
              const unsigned short* __restrict__ Wvb,
              const float* __restrict__ bq, const float* __restrict__ bk,
              const float* __restrict__ bv,
              unsigned short* __restrict__ Qb, unsigned short* __restrict__ Kb,
              unsigned short* __restrict__ Vt)
{
    __shared__ unsigned short sA[128*32];   // 8 KB bf16 A tile
    __shared__ unsigned short sB[128*32];   // 8 KB bf16 W tile

    const int tid = threadIdx.x, lane = tid & 63, w4 = tid >> 6;
    const int m16 = lane & 15, q4 = lane >> 4;
    const int wr = w4 >> 1, wc = w4 & 1;   // 2x2 wave grid -> 64x64 per wave
    const int z = blockIdx.z;

    int id = blockIdx.x + 8 * blockIdx.y;
    int j  = id >> 3;
    const int m0 = ((id & 7) * 4 + (j & 3)) * 128;
    const int n0 = (j >> 2) * 128;

    const unsigned short* A = (z == 0) ? Qa : (z == 1) ? Ka : Va;
    const unsigned short* W = (z == 0) ? Wqb : (z == 1) ? Wkb : Wvb;
    const float* bias = (z == 0) ? bq : (z == 1) ? bk : bv;
    unsigned short* outp = (z == 0) ? Qb : (z == 1) ? Kb : Vt;

    const int G1 = tid + 256;
    const int r0 = tid >> 2, g0 = (tid & 3) ^ ((r0 ^ (r0 >> 2)) & 3);
    const int r1 = G1  >> 2, g1 = (G1  & 3) ^ ((r1 ^ (r1 >> 2)) & 3);
    const char* gA0 = (const char*)A + (size_t)(m0 + r0) * 2048 + g0 * 16;
    const char* gA1 = (const char*)A + (size_t)(m0 + r1) * 2048 + g1 * 16;
    const char* gB0 = (const char*)W + (size_t)(n0 + r0) * 2048 + g0 * 16;
    const char* gB1 = (const char*)W + (size_t)(n0 + r1) * 2048 + g1 * 16;
    char* ldsA0 = (char*)sA + w4 * 1024;
    char* ldsA1 = (char*)sA + 4096 + w4 * 1024;
    char* ldsB0 = (char*)sB + w4 * 1024;
    char* ldsB1 = (char*)sB + 4096 + w4 * 1024;

    int offA[4], offB[4];
    #pragma unroll
    for (int rt = 0; rt < 4; rt++) {
        int r = wr * 64 + rt * 16 + m16;
        offA[rt] = r * 32 + ((q4 ^ ((r ^ (r >> 2)) & 3)) << 3);
    }
    #pragma unroll
    for (int ct = 0; ct < 4; ct++) {
        int r = wc * 64 + ct * 16 + m16;
        offB[ct] = r * 32 + ((q4 ^ ((r ^ (r >> 2)) & 3)) << 3);
    }

    f32x4 acc[4][4];
    const f32x4 zero4 = {0.f, 0.f, 0.f, 0.f};
    #pragma unroll
    for (int i = 0; i < 4; i++)
        #pragma unroll
        for (int jj = 0; jj < 4; jj++) acc[i][jj] = zero4;

    for (int k0 = 0; k0 < DM; k0 += 32) {
        async16(ldsA0, gA0);
        async16(ldsA1, gA1);
        async16(ldsB0, gB0);
        async16(ldsB1, gB1);
        gA0 += 64; gA1 += 64; gB0 += 64; gB1 += 64;
        __syncthreads();

        bfrag a[4], bb[4];
        #pragma unroll
        for (int rt = 0; rt < 4; rt++) a[rt]  = *(const bfrag*)&sA[offA[rt]];
        #pragma unroll
        for (int ct = 0; ct < 4; ct++) bb[ct] = *(const bfrag*)&sB[offB[ct]];

        #pragma unroll
        for (int rt = 0; rt < 4; rt++)
            #pragma unroll
            for (int ct = 0; ct < 4; ct++)
                acc[rt][ct] = mfma16(a[rt], bb[ct], acc[rt][ct]);
        __syncthreads();
    }

    const float SCALE = (z == 0) ? 0.18033688011112042f : 1.0f; // log2(e)/8
    #pragma unroll
    for (int rt = 0; rt < 4; rt++)
        #pragma unroll
        for (int ct = 0; ct < 4; ct++)
            #pragma unroll
            for (int reg = 0; reg < 4; reg++) {
                int r = m0 + wr * 64 + rt * 16 + q4 * 4 + reg;
                int c = n0 + wc * 64 + ct * 16 + m16;
                float v = (acc[rt][ct][reg] + bias[c]) * SCALE;
                int s = r >> 1, b = r & 1, hh = c >> 6, d = c & 63;
                unsigned short bv16 = bf16_rn(v);
                if (z == 2)
                    outp[((size_t)(b * NH + hh) * HD + d) * S_LEN + s] = bv16;
                else
                    outp[((size_t)(b * NH + hh) * S_LEN + s) * HD + d] = bv16;
            }
}

// ---------------------------------------------------------------------------
// Attention, t-split x2 for occupancy (R7: 67 us at Occupancy 18%, grid-limited
// to 2 blocks/CU; latency-bound, pipe-busy floor ~15 us). 1024 blocks, each
// handles ONE HALF of the t-range (16 tiles). Fixed-base exp2 makes partials
// exactly additive: block writes unnormalized O (bf16, into d_out scratch)
// and l (fp32); cmb_kernel combines. l accumulates raw exp2 outputs (VALU
// shave; ~1e-4 relative inconsistency vs rounded P is negligible).
// ---------------------------------------------------------------------------
__global__ __launch_bounds__(256)
void attn_kernel(const unsigned short* __restrict__ Qb,
                 const unsigned short* __restrict__ Kb,
                 const unsigned short* __restrict__ Vt,
                 unsigned short* __restrict__ Op,   // [2][BATCH*NH][S][HD] bf16
                 float* __restrict__ Lp)            // [2][BATCH*NH*S] fp32
{
    __shared__ unsigned short sK[2][64*64];    // 2 x 8 KB, XOR-swizzled rows
    __shared__ unsigned short sV[2][64*64];    // 2 x 8 KB
    __shared__ unsigned int   sPT[4][32*36];   // per-wave P^T hop, 144B rows

    const int tid = threadIdx.x, lane = tid & 63, w4 = tid >> 6;
    const int m16 = lane & 15, q4 = lane >> 4;

    int id = blockIdx.x;                 // 0..1023
    int xcd = id & 7, j = id >> 3;       // j 0..127
    const int bh   = xcd * 4 + (j >> 5); // 4 heads per XCD
    const int rem  = j & 31;
    const int half = rem & 1;            // t-range half
    const int qc   = rem >> 1;           // 0..15
    const int qw   = qc * 128 + w4 * 32;
    const int tbase = half * (S_LEN / 2);

    const unsigned short* Qp = Qb + (size_t)bh * (S_LEN * HD);
    const unsigned short* Kp = Kb + (size_t)bh * (S_LEN * HD);
    const unsigned short* Vp = Vt + (size_t)bh * (S_LEN * HD);
    unsigned int* pw = sPT[w4];

    // Q B-fragments (fixed for whole kernel): [n=q=lane&15][k=d]
    bfrag aq[2][2];
    #pragma unroll
    for (int nt = 0; nt < 2; nt++)
        #pragma unroll
        for (int kc = 0; kc < 2; kc++)
            aq[nt][kc] = *(const bfrag*)&Qp[(size_t)(qw + nt*16 + m16) * HD + kc*32 + q4*8];

    // staging: 512 granules (16B) per matrix, 2 async16 per thread per matrix.
    const int r0 = tid >> 3,         g0 = (tid & 7) ^ (r0 & 7);
    const int r1 = (tid + 256) >> 3, g1 = (tid & 7) ^ (r1 & 7);
    const char* gK0 = (const char*)Kp + (size_t)(tbase + r0) * 128 + g0 * 16;
    const char* gK1 = (const char*)Kp + (size_t)(tbase + r1) * 128 + g1 * 16;
    const char* gV0 = (const char*)Vp + (size_t)r0 * 4096 + tbase * 2 + g0 * 16;
    const char* gV1 = (const char*)Vp + (size_t)r1 * 4096 + tbase * 2 + g1 * 16;
    const int ldsw = w4 * 1024;

    const f32x4 zero4 = {0.f, 0.f, 0.f, 0.f};
    f32x4 O[2][4];
    float lp[2] = {0.f, 0.f};
    #pragma unroll
    for (int nt = 0; nt < 2; nt++)
        #pragma unroll
        for (int dt = 0; dt < 4; dt++) O[nt][dt] = zero4;

    // prefetch tile 0 into buffer 0
    async16((char*)sK[0] + ldsw,        gK0);
    async16((char*)sK[0] + 4096 + ldsw, gK1);
    async16((char*)sV[0] + ldsw,        gV0);
    async16((char*)sV[0] + 4096 + ldsw, gV1);

    const int NT = (S_LEN / 2) / 64;     // 16 tiles per half
    for (int it = 0; it < NT; it++) {
        const int bi = it & 1;
        __syncthreads();   // drains async (cur tile ready) + prior compute done
        if (it + 1 < NT) {
            size_t ko = (size_t)(it + 1) * 8192, vo = (size_t)(it + 1) * 128;
            async16((char*)sK[bi^1] + ldsw,        gK0 + ko);
            async16((char*)sK[bi^1] + 4096 + ldsw, gK1 + ko);
            async16((char*)sV[bi^1] + ldsw,        gV0 + vo);
            async16((char*)sV[bi^1] + 4096 + ldsw, gV1 + vo);
        }

        const unsigned short* kb = sK[bi];
        const unsigned short* vb = sV[bi];

        // K A-frags [m=t][k=d] from swizzled LDS
        bfrag ak[4][2];
        #pragma unroll
        for (int mt = 0; mt < 4; mt++) {
            int r = mt*16 + m16, s = r & 7;
            ak[mt][0] = *(const bfrag*)&kb[r*64 + ((q4     ^ s) << 3)];
            ak[mt][1] = *(const bfrag*)&kb[r*64 + (((4+q4) ^ s) << 3)];
        }

        // S^T = K.Q^T, then p = exp2(s), RHU-pack P^T; l from raw p (additive)
        #pragma unroll
        for (int nt = 0; nt < 2; nt++) {
            f32x4 Sc[4];
            #pragma unroll
            for (int mt = 0; mt < 4; mt++) {
                Sc[mt] = mfma16(ak[mt][0], aq[nt][0], zero4);
                Sc[mt] = mfma16(ak[mt][1], aq[nt][1], Sc[mt]);
            }
            unsigned rowb = (unsigned)(nt*16 + m16) * 36;
            #pragma unroll
            for (int mt = 0; mt < 4; mt++) {
                float p0 = EXP2F(Sc[mt][0]), p1 = EXP2F(Sc[mt][1]);
                float p2 = EXP2F(Sc[mt][2]), p3 = EXP2F(Sc[mt][3]);
                lp[nt] += (p0 + p1) + (p2 + p3);
                uint2 c2 = { pack_rhu(p0, p1), pack_rhu(p2, p3) };
                *(uint2*)&pw[rowb + mt*8 + q4*2] = c2;
            }
        }

        // V^T A-frags [m=d][k=t] from swizzled LDS
        bfrag av[4][2];
        #pragma unroll
        for (int dt = 0; dt < 4; dt++) {
            int r = dt*16 + m16, s = r & 7;
            av[dt][0] = *(const bfrag*)&vb[r*64 + ((q4     ^ s) << 3)];
            av[dt][1] = *(const bfrag*)&vb[r*64 + (((4+q4) ^ s) << 3)];
        }

        // O^T += V^T . P^T  (P^T B-frags: [n=q=lane&15][k=t=quad*8+j])
        #pragma unroll
        for (int nt = 0; nt < 2; nt++) {
            bfrag bp[2];
            #pragma unroll
            for (int kc = 0; kc < 2; kc++)
                bp[kc] = __builtin_bit_cast(bfrag,
                    *(const i32x4_t*)&pw[(unsigned)(nt*16 + m16) * 36 + kc*16 + q4*4]);
            #pragma unroll
            for (int dt = 0; dt < 4; dt++) {
                O[nt][dt] = mfma16(av[dt][0], bp[0], O[nt][dt]);
                O[nt][dt] = mfma16(av[dt][1], bp[1], O[nt][dt]);
            }
        }
    }

    // epilogue: reduce l over quads, write UNNORMALIZED bf16 O partial + l
    const size_t OPH = (size_t)BATCH * NH * S_LEN * HD;  // 4,194,304 elems
    unsigned short* Ob = Op + (size_t)half * OPH;
    float* Lb = Lp + (size_t)half * (BATCH * NH * S_LEN);
    #pragma unroll
    for (int nt = 0; nt < 2; nt++) {
        float l = lp[nt];
        l += __shfl_xor(l, 16);
        l += __shfl_xor(l, 32);
        int q = qw + nt*16 + m16;
        if (q4 == 0) Lb[(size_t)bh * S_LEN + q] = l;
        size_t rb = ((size_t)bh * S_LEN + q) * HD;
        #pragma unroll
        for (int dt = 0; dt < 4; dt++) {
            u16x4_t o = { bf16_rn(O[nt][dt][0]), bf16_rn(O[nt][dt][1]),
                          bf16_rn(O[nt][dt][2]), bf16_rn(O[nt][dt][3]) };
            *(u16x4_t*)&Ob[rb + dt*16 + q4*4] = o;
        }
    }
}

// ---------------------------------------------------------------------------
// Combine the two t-half partials: Ap = bf16((O0+O1)/(l0+l1)), laid out as
// the out-projection A-plane [r = s*2+b][h*64+d]. ~40 MB traffic, HBM/L2-bound.
// ---------------------------------------------------------------------------
__global__ __launch_bounds__(256)
void cmb_kernel(const unsigned short* __restrict__ Op,
                const float* __restrict__ Lp,
                unsigned short* __restrict__ Ap)
{
    const size_t OPH = (size_t)BATCH * NH * S_LEN * HD;
    int idx = blockIdx.x * 256 + threadIdx.x;     // 524288 threads x 8 elems
    int rho = idx >> 3, dg = idx & 7;             // rho = bh*2048 + q
    size_t e = (size_t)rho * HD + dg * 8;
    float inv = 1.0f / (Lp[rho] + Lp[BATCH*NH*S_LEN + rho]);
    u16x8_t a = *(const u16x8_t*)&Op[e];
    u16x8_t b2 = *(const u16x8_t*)&Op[OPH + e];
    u16x8_t r;
    #pragma unroll
    for (int i = 0; i < 8; i++) {
        float fa = __builtin_bit_cast(float, (unsigned)(unsigned short)a[i]  << 16);
        float fb = __builtin_bit_cast(float, (unsigned)(unsigned short)b2[i] << 16);
        r[i] = bf16_rn((fa + fb) * inv);
    }
    int bh = rho >> 11, q = rho & 2047;
    int b = bh >> 4, h = bh & 15;
    *(u16x8_t*)&Ap[((size_t)(q * 2 + b)) * DM + h * 64 + dg * 8] = r;
}

// ---------------------------------------------------------------------------
// Out projection: d_out = attn @ Wo^T + bo (fp32), 2-phase W split.
// Reshaped to qkv's proven m97 shape: 256 threads, 128x64 tile, 2x2 waves
// (64x32 each), 512 blocks -> 2 blocks/CU (was one 512-thread block/CU).
// ---------------------------------------------------------------------------
__global__ __launch_bounds__(256)
void out_gemm(const unsigned short* __restrict__ Ap,
              const unsigned short* __restrict__ Woh,
              const unsigned short* __restrict__ Wol,
              const float* __restrict__ bo, float* __restrict__ out)
{
    __shared__ unsigned short sA[128*32];   // 8 KB
    __shared__ unsigned short sH[64*32];    // 4 KB
    __shared__ unsigned short sL[64*32];    // 4 KB

    const int tid = threadIdx.x, lane = tid & 63, w4 = tid >> 6;
    const int m16 = lane & 15, q4 = lane >> 4;
    const int wr = w4 >> 1, wc = w4 & 1;    // 2x2 -> 64 M x 32 N per wave

    int id = blockIdx.x + 16 * blockIdx.y;  // 512 blocks
    int j  = id >> 3;                        // 0..63
    const int m0 = ((id & 7) * 4 + (j & 3)) * 128;
    const int n0 = (j >> 2) * 64;

    // A staging: 512 granules, 2/thread; H/L: 256 granules, 1/thread each
    const int G1 = tid + 256;
    const int r0 = tid >> 2, g0 = (tid & 3) ^ ((r0 ^ (r0 >> 2)) & 3);
    const int r1 = G1  >> 2, g1 = (G1  & 3) ^ ((r1 ^ (r1 >> 2)) & 3);
    const char* gA0 = (const char*)Ap  + (size_t)(m0 + r0) * 2048 + g0 * 16;
    const char* gA1 = (const char*)Ap  + (size_t)(m0 + r1) * 2048 + g1 * 16;
    const char* gH  = (const char*)Woh + (size_t)(n0 + r0) * 2048 + g0 * 16;
    const char* gL  = (const char*)Wol + (size_t)(n0 + r0) * 2048 + g0 * 16;
    char* ldsA0 = (char*)sA + w4 * 1024;
    char* ldsA1 = (char*)sA + 4096 + w4 * 1024;
    char* ldsH  = (char*)sH + w4 * 1024;
    char* ldsL  = (char*)sL + w4 * 1024;

    int offA[4], offB[2];
    #pragma unroll
    for (int rt = 0; rt < 4; rt++) {
        int r = wr * 64 + rt * 16 + m16;
        offA[rt] = r * 32 + ((q4 ^ ((r ^ (r >> 2)) & 3)) << 3);
    }
    #pragma unroll
    for (int ct = 0; ct < 2; ct++) {
        int r = wc * 32 + ct * 16 + m16;
        offB[ct] = r * 32 + ((q4 ^ ((r ^ (r >> 2)) & 3)) << 3);
    }

    f32x4 acc[4][2];
    const f32x4 zero4 = {0.f, 0.f, 0.f, 0.f};
    #pragma unroll
    for (int i = 0; i < 4; i++)
        #pragma unroll
        for (int jj = 0; jj < 2; jj++) acc[i][jj] = zero4;

    for (int k0 = 0; k0 < DM; k0 += 32) {
        async16(ldsA0, gA0);
        async16(ldsA1, gA1);
        async16(ldsH,  gH);
        async16(ldsL,  gL);
        gA0 += 64; gA1 += 64; gH += 64; gL += 64;
        __syncthreads();

        bfrag a[4], bh2[2], bl2[2];
        #pragma unroll
        for (int rt = 0; rt < 4; rt++) a[rt] = *(const bfrag*)&sA[offA[rt]];
        #pragma unroll
        for (int ct = 0; ct < 2; ct++) {
            bh2[ct] = *(const bfrag*)&sH[offB[ct]];
            bl2[ct] = *(const bfrag*)&sL[offB[ct]];
        }
        #pragma unroll
        for (int rt = 0; rt < 4; rt++)
            #pragma unroll
            for (int ct = 0; ct < 2; ct++) {
                acc[rt][ct] = mfma16(a[rt], bh2[ct], acc[rt][ct]);
                acc[rt][ct] = mfma16(a[rt], bl2[ct], acc[rt][ct]);
            }
        __syncthreads();
    }

    #pragma unroll
    for (int rt = 0; rt < 4; rt++)
        #pragma unroll
        for (int ct = 0; ct < 2; ct++)
            #pragma unroll
            for (int reg = 0; reg < 4; reg++) {
                int r = m0 + wr * 64 + rt * 16 + q4 * 4 + reg;
                int c = n0 + wc * 32 + ct * 16 + m16;
                out[(size_t)r * DM + c] = acc[rt][ct][reg] + bo[c];
            }
}

// ---------------------------------------------------------------------------
extern "C" void kernel_launch(void* const* d_in, const int* in_sizes, int n_in,
                              void* d_out, int out_size, void* d_ws, size_t ws_size,
                              hipStream_t stream)
{
    const float* query = (const float*)d_in[0];
    const float* key   = (const float*)d_in[1];
    const float* value = (const float*)d_in[2];
    const float* Wq    = (const float*)d_in[3];
    const float* bq    = (const float*)d_in[4];
    const float* Wk    = (const float*)d_in[5];
    const float* bk    = (const float*)d_in[6];
    const float* Wv    = (const float*)d_in[7];
    const float* bv    = (const float*)d_in[8];
    const float* Wo    = (const float*)d_in[9];
    const float* bo    = (const float*)d_in[10];

    char* ws = (char*)d_ws;
    const size_t MB = 1u << 20;
    unsigned short* Qb  = (unsigned short*)(ws);            //  0..8 MB
    unsigned short* Kb  = (unsigned short*)(ws +  8*MB);    //  8..16
    unsigned short* Vt  = (unsigned short*)(ws + 16*MB);    // 16..24
    unsigned short* Woh = (unsigned short*)(ws + 24*MB);    // 24..26 (live till out)
    unsigned short* Wol = (unsigned short*)(ws + 26*MB);    // 26..28
    unsigned short* Wqb = (unsigned short*)(ws + 28*MB);    // 28..30 (dead after qkv)
    unsigned short* Wkb = (unsigned short*)(ws + 30*MB);    // 30..32 (dead after qkv)
    unsigned short* Wvb = (unsigned short*)(ws + 32*MB);    // 32..34 (dead after qkv)
    unsigned short* Va  = (unsigned short*)(ws + 34*MB);    // 34..42 (dead after qkv)
    float*          Lp  = (float*)         (ws + 28*MB);    // 28..28.5 (attn l partials,
                                                            //   over dead Wqb)
    unsigned short* Apl = (unsigned short*)(ws + 34*MB);    // 34..42 (combined A-plane,
                                                            //   over dead Va)
    // O partials (2 x 8 MB bf16) live in d_out (free between qkv and out_gemm).
    unsigned short* Opart = (unsigned short*)d_out;
    // Qa/Ka bf16 A-planes also live in d_out during cvt+qkv.
    unsigned short* Qa  = (unsigned short*)d_out;                    // d_out 0..8 MB
    unsigned short* Ka  = (unsigned short*)d_out + (size_t)MROWS*DM; // 8..16 MB
    // peak ws footprint: 42 MB (same as R7)

    cvt_kernel<<<dim3(2048, 1, 7), 256, 0, stream>>>(
        Wq, Wk, Wv, Wo, query, key, value,
        Wqb, Wkb, Wvb, Woh, Wol, Qa, Ka, Va);
    qkv_gemm<<<dim3(8, 32, 3), 256, 0, stream>>>(
        Qa, Ka, Va, Wqb, Wkb, Wvb, bq, bk, bv, Qb, Kb, Vt);
    attn_kernel<<<dim3(1024), 256, 0, stream>>>(Qb, Kb, Vt, Opart, Lp);
    cmb_kernel<<<dim3(2048), 256, 0, stream>>>(Opart, Lp, Apl);
    out_gemm<<<dim3(16, 32), 256, 0, stream>>>(Apl, Woh, Wol, bo, (float*)d_out);
}